// Round 1
// baseline (605.314 us; speedup 1.0000x reference)
//
#include <hip/hip_runtime.h>
#include <stdint.h>

#define N_SRCN 50000
#define N_DSTN 50000
#define NE     800000
#define HIDN   256
#define NEG    0.2f

typedef __attribute__((ext_vector_type(8)))  short short8;
typedef __attribute__((ext_vector_type(16))) float float16v;

__device__ __forceinline__ float bf2f(unsigned short u){
    union { unsigned u32; float f; } c; c.u32 = ((unsigned)u) << 16; return c.f;
}
__device__ __forceinline__ unsigned short f2bf(float f){
    union { float f; unsigned u; } c; c.f = f;
    unsigned r = c.u + 0x7fffu + ((c.u >> 16) & 1u);
    return (unsigned short)(r >> 16);
}
__device__ __forceinline__ float4 ld4b(const unsigned short* p){
    uint2 u = *reinterpret_cast<const uint2*>(p);
    float4 r;
    r.x = bf2f((unsigned short)(u.x & 0xffff));
    r.y = bf2f((unsigned short)(u.x >> 16));
    r.z = bf2f((unsigned short)(u.y & 0xffff));
    r.w = bf2f((unsigned short)(u.y >> 16));
    return r;
}

// ---- pack weights, input-indexed (coalesced reads, scattered 2B writes) ----
// Wt2: [which(3)][cb(8)][kk(4)][lane(64)][8]   (49152)
// Wf : [g(3)][cb(8)][kk(32)][lane(64)][8]      (393216), K=512 = [Wih|Whh]
__global__ void pack_kernel(const float* __restrict__ Wsrc, const float* __restrict__ Wdst,
                            const float* __restrict__ Wres, const float* __restrict__ Wih,
                            const float* __restrict__ Whh,
                            unsigned short* __restrict__ Wt2,
                            unsigned short* __restrict__ Wf){
    int i = blockIdx.x * 256 + threadIdx.x;
    if (i < 49152){
        int which = i >> 14, j = i & 16383;          // j = k*256 + c
        int k = j >> 8, c = j & 255;
        const float* W = (which == 0) ? Wsrc : (which == 1 ? Wdst : Wres);
        float v = W[j];
        int off = which * 16384 + (c >> 5) * 2048 + (k >> 4) * 512
                + (((k >> 3) & 1) * 32 + (c & 31)) * 8 + (k & 7);
        Wt2[off] = f2bf(v);
    } else if (i < 49152 + 196608){
        int o = i - 49152;                            // Wih flat: (g*256+c)*256+k
        int row = o >> 8, k = o & 255;
        int g = row >> 8, c = row & 255;
        float v = Wih[o];
        int off = g * 131072 + (c >> 5) * 16384 + (k >> 4) * 512
                + (((k >> 3) & 1) * 32 + (c & 31)) * 8 + (k & 7);
        Wf[off] = f2bf(v);
    } else if (i < 49152 + 393216){
        int o = i - 49152 - 196608;                   // Whh
        int row = o >> 8, k = o & 255;
        int g = row >> 8, c = row & 255;
        float v = Whh[o];
        int off = g * 131072 + (c >> 5) * 16384 + (16 + (k >> 4)) * 512
                + (((k >> 3) & 1) * 32 + (c & 31)) * 8 + (k & 7);
        Wf[off] = f2bf(v);
    }
}

// ---- fused projection GEMM (K=64), z selects {src, dst, res} --------------
__global__ __launch_bounds__(256) void proj_kernel(
        const float* __restrict__ Agt, const float* __restrict__ Aag,
        const unsigned short* __restrict__ Wt2,
        const float* __restrict__ bsrc, const float* __restrict__ bdst,
        const float* __restrict__ bres,
        unsigned short* __restrict__ fs, unsigned short* __restrict__ fd,
        unsigned short* __restrict__ resb){
    __shared__ unsigned short As[64 * 72];
    __shared__ unsigned short Cs[64 * 72];
    int z = blockIdx.z;
    const float* A = (z == 0) ? Agt : Aag;
    const float* bias = (z == 0) ? bsrc : (z == 1 ? bdst : bres);
    unsigned short* out = (z == 0) ? fs : (z == 1 ? fd : resb);
    const unsigned short* Wb = Wt2 + z * 16384;
    int tid = threadIdx.x;
    int m0 = blockIdx.y * 64;
    #pragma unroll
    for (int i = 0; i < 4; ++i){
        int ci = tid + i * 256;
        int row = ci >> 4;
        int k4 = (ci & 15) << 2;
        int gr = m0 + row; if (gr >= N_SRCN) gr = N_SRCN - 1;
        float4 v = *reinterpret_cast<const float4*>(A + (size_t)gr * 64 + k4);
        unsigned short* dp = As + row * 72 + k4;
        dp[0] = f2bf(v.x); dp[1] = f2bf(v.y); dp[2] = f2bf(v.z); dp[3] = f2bf(v.w);
    }
    __syncthreads();
    int lane = tid & 63, w = tid >> 6;
    int l31 = lane & 31, half = lane >> 5;
    int msub = (w & 1) * 32;
    int cbw = blockIdx.x * 2 + (w >> 1);
    const unsigned short* bb = Wb + cbw * 2048 + lane * 8;
    const unsigned short* ap = As + (msub + l31) * 72 + half * 8;
    float16v acc = {0,0,0,0,0,0,0,0,0,0,0,0,0,0,0,0};
    #pragma unroll
    for (int ks = 0; ks < 4; ++ks){
        short8 a = *reinterpret_cast<const short8*>(ap + ks * 16);
        short8 b = *reinterpret_cast<const short8*>(bb + ks * 512);
        acc = __builtin_amdgcn_mfma_f32_32x32x16_bf16(a, b, acc, 0, 0, 0);
    }
    float bv = bias[cbw * 32 + l31];
    int ccol = (w >> 1) * 32 + l31;
    #pragma unroll
    for (int r = 0; r < 16; ++r){
        int row = (r & 3) + 8 * (r >> 2) + 4 * half + msub;
        Cs[row * 72 + ccol] = f2bf(acc[r] + bv);
    }
    __syncthreads();
    int srow = tid >> 2, chunk = tid & 3;
    int gr2 = m0 + srow;
    if (gr2 < N_SRCN){
        const uint4* sp = reinterpret_cast<const uint4*>(Cs + srow * 72 + chunk * 16);
        uint4* gp = reinterpret_cast<uint4*>(out + (size_t)gr2 * 256 + blockIdx.x * 64 + chunk * 16);
        gp[0] = sp[0];
        gp[1] = sp[1];
    }
}

// ---- edge CSR build -------------------------------------------------------
__global__ void degree_kernel(const int* __restrict__ dst, int* __restrict__ deg){
    int i = blockIdx.x * 256 + threadIdx.x;
    if (i < NE) atomicAdd(&deg[dst[i]], 1);
}

__global__ void scan1_kernel(const int* __restrict__ deg, int* __restrict__ bsum){
    __shared__ int s[256];
    int tid = threadIdx.x;
    int i = blockIdx.x * 256 + tid;
    s[tid] = (i < N_DSTN) ? deg[i] : 0;
    __syncthreads();
    #pragma unroll
    for (int off = 128; off; off >>= 1){
        if (tid < off) s[tid] += s[tid + off];
        __syncthreads();
    }
    if (tid == 0) bsum[blockIdx.x] = s[0];
}

__global__ void scan2_kernel(const int* __restrict__ bsum, int* __restrict__ boff){
    __shared__ int s[256];
    int tid = threadIdx.x;
    int v = (tid < 196) ? bsum[tid] : 0;
    s[tid] = v;
    __syncthreads();
    #pragma unroll
    for (int off = 1; off < 256; off <<= 1){
        int t = (tid >= off) ? s[tid - off] : 0;
        __syncthreads();
        s[tid] += t;
        __syncthreads();
    }
    if (tid < 196) boff[tid] = s[tid] - v;
}

__global__ void scan3_kernel(const int* __restrict__ deg, const int* __restrict__ boff,
                             int* __restrict__ ptr, int* __restrict__ cursor){
    __shared__ int s[256];
    int tid = threadIdx.x;
    int i = blockIdx.x * 256 + tid;
    int v = (i < N_DSTN) ? deg[i] : 0;
    s[tid] = v;
    __syncthreads();
    #pragma unroll
    for (int off = 1; off < 256; off <<= 1){
        int t = (tid >= off) ? s[tid - off] : 0;
        __syncthreads();
        s[tid] += t;
        __syncthreads();
    }
    int ex = s[tid] - v + boff[blockIdx.x];
    if (i < N_DSTN){ ptr[i] = ex; cursor[i] = ex; }
}

__global__ void scatter_kernel(const int* __restrict__ src, const int* __restrict__ dst,
                               int* __restrict__ cursor, int* __restrict__ csr){
    int i = blockIdx.x * 256 + threadIdx.x;
    if (i < NE){
        int d = dst[i];
        int pos = atomicAdd(&cursor[d], 1);
        csr[pos] = src[i];
    }
}

// ---- per-dst aggregation, no online max (exp safe here), 4-deep pipeline --
__global__ __launch_bounds__(256) void aggregate_kernel(
        const unsigned short* __restrict__ fs, const unsigned short* __restrict__ fd,
        const unsigned short* __restrict__ res, const float* __restrict__ attn,
        const int* __restrict__ ptr, const int* __restrict__ deg,
        const int* __restrict__ csr, unsigned short* __restrict__ x){
    int wv = threadIdx.x >> 6;
    int d = blockIdx.x * 4 + wv;
    if (d >= N_DSTN) return;
    int lane = threadIdx.x & 63;
    int c4 = lane * 4;
    float4 fdv = ld4b(fd + (size_t)d * 256 + c4);
    float4 at = *reinterpret_cast<const float4*>(attn + (lane >> 4) * 64 + (lane & 15) * 4);
    int p = ptr[d], dg = deg[d];
    float l = 0.f;
    float4 acc = make_float4(0.f, 0.f, 0.f, 0.f);
    for (int base = 0; base < dg; base += 64){
        int cnt = min(64, dg - base);
        int sreg = (lane < cnt) ? csr[p + base + lane] : 0;
        float4 b0 = ld4b(fs + (size_t)__shfl(sreg, 0) * 256 + c4);
        float4 b1 = ld4b(fs + (size_t)__shfl(sreg, 1 & 63) * 256 + c4);
        float4 b2 = ld4b(fs + (size_t)__shfl(sreg, 2 & 63) * 256 + c4);
        float4 b3 = ld4b(fs + (size_t)__shfl(sreg, 3 & 63) * 256 + c4);
        for (int j = 0; j < cnt; j += 4){
            float4 n0 = ld4b(fs + (size_t)__shfl(sreg, (j + 4) & 63) * 256 + c4);
            float4 n1 = ld4b(fs + (size_t)__shfl(sreg, (j + 5) & 63) * 256 + c4);
            float4 n2 = ld4b(fs + (size_t)__shfl(sreg, (j + 6) & 63) * 256 + c4);
            float4 n3 = ld4b(fs + (size_t)__shfl(sreg, (j + 7) & 63) * 256 + c4);
#define PROC(BV, T) { \
            float ex = BV.x + fdv.x; ex = ex > 0.f ? ex : NEG * ex; \
            float ey = BV.y + fdv.y; ey = ey > 0.f ? ey : NEG * ey; \
            float ez = BV.z + fdv.z; ez = ez > 0.f ? ez : NEG * ez; \
            float ew = BV.w + fdv.w; ew = ew > 0.f ? ew : NEG * ew; \
            float part = ex * at.x + ey * at.y + ez * at.z + ew * at.w; \
            part += __shfl_xor(part, 1); \
            part += __shfl_xor(part, 2); \
            part += __shfl_xor(part, 4); \
            part += __shfl_xor(part, 8); \
            float wgt = ((j + (T)) < cnt) ? __expf(part) : 0.f; \
            l += wgt; \
            acc.x = fmaf(wgt, BV.x, acc.x); \
            acc.y = fmaf(wgt, BV.y, acc.y); \
            acc.z = fmaf(wgt, BV.z, acc.z); \
            acc.w = fmaf(wgt, BV.w, acc.w); }
            PROC(b0, 0) PROC(b1, 1) PROC(b2, 2) PROC(b3, 3)
#undef PROC
            b0 = n0; b1 = n1; b2 = n2; b3 = n3;
        }
    }
    float inv = (l > 0.f) ? 1.f / l : 0.f;
    float4 rv = ld4b(res + (size_t)d * 256 + c4);
    float xx = fmaxf(fmaf(acc.x, inv, rv.x), 0.f);
    float xy = fmaxf(fmaf(acc.y, inv, rv.y), 0.f);
    float xz = fmaxf(fmaf(acc.z, inv, rv.z), 0.f);
    float xw = fmaxf(fmaf(acc.w, inv, rv.w), 0.f);
    uint2 o;
    o.x = (unsigned)f2bf(xx) | ((unsigned)f2bf(xy) << 16);
    o.y = (unsigned)f2bf(xz) | ((unsigned)f2bf(xw) << 16);
    *reinterpret_cast<uint2*>(x + (size_t)d * 256 + c4) = o;
}

// ---- GRU v5: 64-row x 256-col full-fusion blocks, K=512 staged ONCE -------
// 512 threads / 8 waves. Wave w: row-tile rt=w>>2 (2x32 rows), col-pair
// cp=w&3 (2 col-tiles of 32). Per wave 8 accs: {r,z,nx,nh} x 2 col-tiles.
// LDS: 64 rows x 512 bf16 = exactly 64KB, XOR-swizzled 16B chunks
// (c ^= row&7) -> same conflict-free bank pattern as v4 (measured 0).
// H0 f32->bf16 conversion happens exactly once per element (rows are
// partitioned across blocks), vs 8x redundant in v4. ONE barrier per block.
__global__ __launch_bounds__(512, 2) void gru_kernel(
        const unsigned short* __restrict__ Xb,
        const float* __restrict__ H0, const unsigned short* __restrict__ Wf,
        const float* __restrict__ bih, const float* __restrict__ bhh,
        float* __restrict__ outH){
    __shared__ unsigned short As[64 * 512];
    int tid = threadIdx.x;
    int m0 = blockIdx.x << 6;
    // stage X half: 64 rows x 256 bf16 (chunks 0..31 of each row)
    #pragma unroll
    for (int i = 0; i < 4; ++i){
        int ci = tid + i * 512;
        int row = ci >> 5, c = ci & 31;
        int gr = m0 + row; if (gr >= N_DSTN) gr = N_DSTN - 1;
        *reinterpret_cast<uint4*>(As + row * 512 + ((c ^ (row & 7)) << 3)) =
            *reinterpret_cast<const uint4*>(Xb + (size_t)gr * 256 + (c << 3));
    }
    // stage H half: 64 rows x 256 f32 -> bf16 (chunks 32..63 of each row)
    #pragma unroll
    for (int i = 0; i < 4; ++i){
        int ci = tid + i * 512;
        int row = ci >> 5, c = ci & 31;
        int gr = m0 + row; if (gr >= N_DSTN) gr = N_DSTN - 1;
        const float* hp = H0 + (size_t)gr * 256 + (c << 3);
        float4 f0 = *reinterpret_cast<const float4*>(hp);
        float4 f1 = *reinterpret_cast<const float4*>(hp + 4);
        uint4 o;
        o.x = (unsigned)f2bf(f0.x) | ((unsigned)f2bf(f0.y) << 16);
        o.y = (unsigned)f2bf(f0.z) | ((unsigned)f2bf(f0.w) << 16);
        o.z = (unsigned)f2bf(f1.x) | ((unsigned)f2bf(f1.y) << 16);
        o.w = (unsigned)f2bf(f1.z) | ((unsigned)f2bf(f1.w) << 16);
        *reinterpret_cast<uint4*>(As + row * 512 + (((c + 32) ^ (row & 7)) << 3)) = o;
    }
    __syncthreads();
    int w = tid >> 6, lane = tid & 63;
    int l31 = lane & 31, half = lane >> 5;
    int rt = w >> 2, cp = w & 3;
    int arow = rt * 32 + l31;
    int rl = arow & 7;
    const unsigned short* apb = As + arow * 512;
    const unsigned short* b0r = Wf + (size_t)(2 * cp) * 16384 + lane * 8;
    const unsigned short* b0z = b0r + 131072;
    const unsigned short* b0n = b0r + 262144;
    const unsigned short* b1r = b0r + 16384;
    const unsigned short* b1z = b1r + 131072;
    const unsigned short* b1n = b1r + 262144;
    float16v zv = {0,0,0,0,0,0,0,0,0,0,0,0,0,0,0,0};
    float16v ar0 = zv, az0 = zv, an0 = zv, ah0 = zv;
    float16v ar1 = zv, az1 = zv, an1 = zv, ah1 = zv;
    // K-part 1: X @ Wih (kk 0..15), n-gate into an*
    #pragma unroll
    for (int kk = 0; kk < 16; ++kk){
        short8 a = *reinterpret_cast<const short8*>(apb + (((kk * 2 + half) ^ rl) << 3));
        short8 vr0 = *reinterpret_cast<const short8*>(b0r + kk * 512);
        short8 vz0 = *reinterpret_cast<const short8*>(b0z + kk * 512);
        short8 vn0 = *reinterpret_cast<const short8*>(b0n + kk * 512);
        short8 vr1 = *reinterpret_cast<const short8*>(b1r + kk * 512);
        short8 vz1 = *reinterpret_cast<const short8*>(b1z + kk * 512);
        short8 vn1 = *reinterpret_cast<const short8*>(b1n + kk * 512);
        ar0 = __builtin_amdgcn_mfma_f32_32x32x16_bf16(a, vr0, ar0, 0, 0, 0);
        az0 = __builtin_amdgcn_mfma_f32_32x32x16_bf16(a, vz0, az0, 0, 0, 0);
        an0 = __builtin_amdgcn_mfma_f32_32x32x16_bf16(a, vn0, an0, 0, 0, 0);
        ar1 = __builtin_amdgcn_mfma_f32_32x32x16_bf16(a, vr1, ar1, 0, 0, 0);
        az1 = __builtin_amdgcn_mfma_f32_32x32x16_bf16(a, vz1, az1, 0, 0, 0);
        an1 = __builtin_amdgcn_mfma_f32_32x32x16_bf16(a, vn1, an1, 0, 0, 0);
    }
    // K-part 2: H @ Whh (kk 16..31), n-gate into ah*
    #pragma unroll
    for (int kk = 16; kk < 32; ++kk){
        short8 a = *reinterpret_cast<const short8*>(apb + (((kk * 2 + half) ^ rl) << 3));
        short8 vr0 = *reinterpret_cast<const short8*>(b0r + kk * 512);
        short8 vz0 = *reinterpret_cast<const short8*>(b0z + kk * 512);
        short8 vn0 = *reinterpret_cast<const short8*>(b0n + kk * 512);
        short8 vr1 = *reinterpret_cast<const short8*>(b1r + kk * 512);
        short8 vz1 = *reinterpret_cast<const short8*>(b1z + kk * 512);
        short8 vn1 = *reinterpret_cast<const short8*>(b1n + kk * 512);
        ar0 = __builtin_amdgcn_mfma_f32_32x32x16_bf16(a, vr0, ar0, 0, 0, 0);
        az0 = __builtin_amdgcn_mfma_f32_32x32x16_bf16(a, vz0, az0, 0, 0, 0);
        ah0 = __builtin_amdgcn_mfma_f32_32x32x16_bf16(a, vn0, ah0, 0, 0, 0);
        ar1 = __builtin_amdgcn_mfma_f32_32x32x16_bf16(a, vr1, ar1, 0, 0, 0);
        az1 = __builtin_amdgcn_mfma_f32_32x32x16_bf16(a, vz1, az1, 0, 0, 0);
        ah1 = __builtin_amdgcn_mfma_f32_32x32x16_bf16(a, vn1, ah1, 0, 0, 0);
    }
    // fused GRU epilogue; H0 rows are L2-hot (staged by this block above)
#define EPI(AR, AZ, AN, AH, CT) { \
    int cg = (cp * 2 + (CT)) * 32 + l31; \
    float rb = bih[cg] + bhh[cg]; \
    float zb = bih[256 + cg] + bhh[256 + cg]; \
    float bin = bih[512 + cg], bhn = bhh[512 + cg]; \
    _Pragma("unroll") \
    for (int r = 0; r < 16; ++r){ \
        int m = m0 + rt * 32 + (r & 3) + 8 * (r >> 2) + 4 * half; \
        if (m < N_DSTN){ \
            float h0v = H0[(size_t)m * 256 + cg]; \
            float rrg = 1.f / (1.f + __expf(-((AR)[r] + rb))); \
            float zg  = 1.f / (1.f + __expf(-((AZ)[r] + zb))); \
            float nx = (AN)[r] + bin + rrg * ((AH)[r] + bhn); \
            float tm = __expf(-2.f * fabsf(nx)); \
            float nn = (1.f - tm) / (1.f + tm); \
            nn = (nx >= 0.f) ? nn : -nn; \
            outH[(size_t)m * 256 + cg] = (1.f - zg) * nn + zg * h0v; \
        } \
    } }
    EPI(ar0, az0, an0, ah0, 0)
    EPI(ar1, az1, an1, ah1, 1)
#undef EPI
}

// ---- logits = h @ W_out + b_out ------------------------------------------
__global__ __launch_bounds__(256) void logits_kernel(
        const float* __restrict__ H, const float* __restrict__ Wout,
        const float* __restrict__ bout, float* __restrict__ outL){
    __shared__ float Hl[16 * 260];
    __shared__ float Wl[16 * 260];
    int tid = threadIdx.x;
    int m0 = blockIdx.x * 16;
    #pragma unroll
    for (int i = 0; i < 4; ++i){
        int ci = tid + i * 256;
        int row = ci >> 6;
        int c4 = (ci & 63) << 2;
        int gr = m0 + row; if (gr >= N_DSTN) gr = N_DSTN - 1;
        float4 v = *reinterpret_cast<const float4*>(H + (size_t)gr * 256 + c4);
        float* dp = Hl + row * 260 + c4;
        dp[0] = v.x; dp[1] = v.y; dp[2] = v.z; dp[3] = v.w;
    }
    #pragma unroll
    for (int i = 0; i < 16; ++i){
        int ci = tid + i * 256;
        int c = ci >> 4, j = ci & 15;
        Wl[j * 260 + c] = Wout[c * 16 + j];
    }
    __syncthreads();
    int row = tid >> 4, j = tid & 15;
    const float* hr = Hl + row * 260;
    const float* wr = Wl + j * 260;
    float acc = bout[j];
    #pragma unroll
    for (int c = 0; c < 256; c += 4){
        float4 hv = *reinterpret_cast<const float4*>(hr + c);
        float4 wv = *reinterpret_cast<const float4*>(wr + c);
        acc = fmaf(hv.x, wv.x, fmaf(hv.y, wv.y, fmaf(hv.z, wv.z, fmaf(hv.w, wv.w, acc))));
    }
    int m = m0 + row;
    if (m < N_DSTN) outL[m * 16 + j] = acc;
}

extern "C" void kernel_launch(void* const* d_in, const int* in_sizes, int n_in,
                              void* d_out, int out_size, void* d_ws, size_t ws_size,
                              hipStream_t stream){
    const float* feat_gt = (const float*)d_in[0];
    const float* feat_ag = (const float*)d_in[1];
    const float* h0      = (const float*)d_in[2];
    const int*   e_src   = (const int*)d_in[3];
    const int*   e_dst   = (const int*)d_in[4];
    const float* W_src   = (const float*)d_in[5];
    const float* b_src   = (const float*)d_in[6];
    const float* W_dst   = (const float*)d_in[7];
    const float* b_dst   = (const float*)d_in[8];
    const float* attn    = (const float*)d_in[9];
    const float* W_res   = (const float*)d_in[10];
    const float* b_res   = (const float*)d_in[11];
    const float* W_ih    = (const float*)d_in[12];
    const float* W_hh    = (const float*)d_in[13];
    const float* b_ih    = (const float*)d_in[14];
    const float* b_hh    = (const float*)d_in[15];
    const float* W_out   = (const float*)d_in[16];
    const float* b_out   = (const float*)d_in[17];

    float* outL = (float*)d_out;
    float* outH = outL + (size_t)N_DSTN * 16;

    char* ws = (char*)d_ws;
    size_t off = 0;
    auto alloc = [&](size_t bytes) -> void* {
        void* p = ws + off; off = (off + bytes + 255) & ~(size_t)255; return p;
    };
    unsigned short* fs   = (unsigned short*)alloc((size_t)N_SRCN * 256 * 2);
    unsigned short* fd   = (unsigned short*)alloc((size_t)N_DSTN * 256 * 2);
    unsigned short* res  = (unsigned short*)alloc((size_t)N_DSTN * 256 * 2);
    unsigned short* xb   = (unsigned short*)alloc((size_t)N_DSTN * 256 * 2);
    unsigned short* Wt2  = (unsigned short*)alloc(49152 * 2);
    unsigned short* Wf   = (unsigned short*)alloc(393216 * 2);
    int* deg    = (int*)alloc(N_DSTN * 4);
    int* ptr    = (int*)alloc(N_DSTN * 4);
    int* cursor = (int*)alloc(N_DSTN * 4);
    int* csr    = (int*)alloc((size_t)NE * 4);
    int* bsum   = (int*)alloc(256 * 4);
    int* boff   = (int*)alloc(256 * 4);

    hipMemsetAsync(deg, 0, N_DSTN * 4, stream);
    pack_kernel<<<1728, 256, 0, stream>>>(W_src, W_dst, W_res, W_ih, W_hh, Wt2, Wf);

    proj_kernel<<<dim3(4, 782, 3), 256, 0, stream>>>(feat_gt, feat_ag, Wt2,
                                                     b_src, b_dst, b_res, fs, fd, res);

    degree_kernel<<<3125, 256, 0, stream>>>(e_dst, deg);
    scan1_kernel<<<196, 256, 0, stream>>>(deg, bsum);
    scan2_kernel<<<1, 256, 0, stream>>>(bsum, boff);
    scan3_kernel<<<196, 256, 0, stream>>>(deg, boff, ptr, cursor);
    scatter_kernel<<<3125, 256, 0, stream>>>(e_src, e_dst, cursor, csr);
    aggregate_kernel<<<12500, 256, 0, stream>>>(fs, fd, res, attn, ptr, deg, csr, xb);

    gru_kernel<<<782, 512, 0, stream>>>(xb, h0, Wf, b_ih, b_hh, outH);
    logits_kernel<<<3125, 256, 0, stream>>>(outH, W_out, b_out, outL);
}

// Round 2
// 486.752 us; speedup vs baseline: 1.2436x; 1.2436x over previous
//
#include <hip/hip_runtime.h>
#include <stdint.h>

#define N_SRCN 50000
#define N_DSTN 50000
#define NE     800000
#define HIDN   256
#define NEG    0.2f

typedef __attribute__((ext_vector_type(8)))  short short8;
typedef __attribute__((ext_vector_type(16))) float float16v;

__device__ __forceinline__ float bf2f(unsigned short u){
    union { unsigned u32; float f; } c; c.u32 = ((unsigned)u) << 16; return c.f;
}
__device__ __forceinline__ unsigned short f2bf(float f){
    union { float f; unsigned u; } c; c.f = f;
    unsigned r = c.u + 0x7fffu + ((c.u >> 16) & 1u);
    return (unsigned short)(r >> 16);
}
__device__ __forceinline__ float4 ld4b(const unsigned short* p){
    uint2 u = *reinterpret_cast<const uint2*>(p);
    float4 r;
    r.x = bf2f((unsigned short)(u.x & 0xffff));
    r.y = bf2f((unsigned short)(u.x >> 16));
    r.z = bf2f((unsigned short)(u.y & 0xffff));
    r.w = bf2f((unsigned short)(u.y >> 16));
    return r;
}

// ---- pack weights, input-indexed (coalesced reads, scattered 2B writes) ----
// Wt2: [which(3)][cb(8)][kk(4)][lane(64)][8]   (49152)
// Wf : [g(3)][cb(8)][kk(32)][lane(64)][8]      (393216), K=512 = [Wih|Whh]
__global__ void pack_kernel(const float* __restrict__ Wsrc, const float* __restrict__ Wdst,
                            const float* __restrict__ Wres, const float* __restrict__ Wih,
                            const float* __restrict__ Whh,
                            unsigned short* __restrict__ Wt2,
                            unsigned short* __restrict__ Wf){
    int i = blockIdx.x * 256 + threadIdx.x;
    if (i < 49152){
        int which = i >> 14, j = i & 16383;          // j = k*256 + c
        int k = j >> 8, c = j & 255;
        const float* W = (which == 0) ? Wsrc : (which == 1 ? Wdst : Wres);
        float v = W[j];
        int off = which * 16384 + (c >> 5) * 2048 + (k >> 4) * 512
                + (((k >> 3) & 1) * 32 + (c & 31)) * 8 + (k & 7);
        Wt2[off] = f2bf(v);
    } else if (i < 49152 + 196608){
        int o = i - 49152;                            // Wih flat: (g*256+c)*256+k
        int row = o >> 8, k = o & 255;
        int g = row >> 8, c = row & 255;
        float v = Wih[o];
        int off = g * 131072 + (c >> 5) * 16384 + (k >> 4) * 512
                + (((k >> 3) & 1) * 32 + (c & 31)) * 8 + (k & 7);
        Wf[off] = f2bf(v);
    } else if (i < 49152 + 393216){
        int o = i - 49152 - 196608;                   // Whh
        int row = o >> 8, k = o & 255;
        int g = row >> 8, c = row & 255;
        float v = Whh[o];
        int off = g * 131072 + (c >> 5) * 16384 + (16 + (k >> 4)) * 512
                + (((k >> 3) & 1) * 32 + (c & 31)) * 8 + (k & 7);
        Wf[off] = f2bf(v);
    }
}

// ---- fused projection GEMM (K=64), z selects {src, dst, res} --------------
__global__ __launch_bounds__(256) void proj_kernel(
        const float* __restrict__ Agt, const float* __restrict__ Aag,
        const unsigned short* __restrict__ Wt2,
        const float* __restrict__ bsrc, const float* __restrict__ bdst,
        const float* __restrict__ bres,
        unsigned short* __restrict__ fs, unsigned short* __restrict__ fd,
        unsigned short* __restrict__ resb){
    __shared__ unsigned short As[64 * 72];
    __shared__ unsigned short Cs[64 * 72];
    int z = blockIdx.z;
    const float* A = (z == 0) ? Agt : Aag;
    const float* bias = (z == 0) ? bsrc : (z == 1 ? bdst : bres);
    unsigned short* out = (z == 0) ? fs : (z == 1 ? fd : resb);
    const unsigned short* Wb = Wt2 + z * 16384;
    int tid = threadIdx.x;
    int m0 = blockIdx.y * 64;
    #pragma unroll
    for (int i = 0; i < 4; ++i){
        int ci = tid + i * 256;
        int row = ci >> 4;
        int k4 = (ci & 15) << 2;
        int gr = m0 + row; if (gr >= N_SRCN) gr = N_SRCN - 1;
        float4 v = *reinterpret_cast<const float4*>(A + (size_t)gr * 64 + k4);
        unsigned short* dp = As + row * 72 + k4;
        dp[0] = f2bf(v.x); dp[1] = f2bf(v.y); dp[2] = f2bf(v.z); dp[3] = f2bf(v.w);
    }
    __syncthreads();
    int lane = tid & 63, w = tid >> 6;
    int l31 = lane & 31, half = lane >> 5;
    int msub = (w & 1) * 32;
    int cbw = blockIdx.x * 2 + (w >> 1);
    const unsigned short* bb = Wb + cbw * 2048 + lane * 8;
    const unsigned short* ap = As + (msub + l31) * 72 + half * 8;
    float16v acc = {0,0,0,0,0,0,0,0,0,0,0,0,0,0,0,0};
    #pragma unroll
    for (int ks = 0; ks < 4; ++ks){
        short8 a = *reinterpret_cast<const short8*>(ap + ks * 16);
        short8 b = *reinterpret_cast<const short8*>(bb + ks * 512);
        acc = __builtin_amdgcn_mfma_f32_32x32x16_bf16(a, b, acc, 0, 0, 0);
    }
    float bv = bias[cbw * 32 + l31];
    int ccol = (w >> 1) * 32 + l31;
    #pragma unroll
    for (int r = 0; r < 16; ++r){
        int row = (r & 3) + 8 * (r >> 2) + 4 * half + msub;
        Cs[row * 72 + ccol] = f2bf(acc[r] + bv);
    }
    __syncthreads();
    int srow = tid >> 2, chunk = tid & 3;
    int gr2 = m0 + srow;
    if (gr2 < N_SRCN){
        const uint4* sp = reinterpret_cast<const uint4*>(Cs + srow * 72 + chunk * 16);
        uint4* gp = reinterpret_cast<uint4*>(out + (size_t)gr2 * 256 + blockIdx.x * 64 + chunk * 16);
        gp[0] = sp[0];
        gp[1] = sp[1];
    }
}

// ---- edge CSR build -------------------------------------------------------
__global__ void degree_kernel(const int* __restrict__ dst, int* __restrict__ deg){
    int i = blockIdx.x * 256 + threadIdx.x;
    if (i < NE) atomicAdd(&deg[dst[i]], 1);
}

__global__ void scan1_kernel(const int* __restrict__ deg, int* __restrict__ bsum){
    __shared__ int s[256];
    int tid = threadIdx.x;
    int i = blockIdx.x * 256 + tid;
    s[tid] = (i < N_DSTN) ? deg[i] : 0;
    __syncthreads();
    #pragma unroll
    for (int off = 128; off; off >>= 1){
        if (tid < off) s[tid] += s[tid + off];
        __syncthreads();
    }
    if (tid == 0) bsum[blockIdx.x] = s[0];
}

__global__ void scan2_kernel(const int* __restrict__ bsum, int* __restrict__ boff){
    __shared__ int s[256];
    int tid = threadIdx.x;
    int v = (tid < 196) ? bsum[tid] : 0;
    s[tid] = v;
    __syncthreads();
    #pragma unroll
    for (int off = 1; off < 256; off <<= 1){
        int t = (tid >= off) ? s[tid - off] : 0;
        __syncthreads();
        s[tid] += t;
        __syncthreads();
    }
    if (tid < 196) boff[tid] = s[tid] - v;
}

__global__ void scan3_kernel(const int* __restrict__ deg, const int* __restrict__ boff,
                             int* __restrict__ ptr, int* __restrict__ cursor){
    __shared__ int s[256];
    int tid = threadIdx.x;
    int i = blockIdx.x * 256 + tid;
    int v = (i < N_DSTN) ? deg[i] : 0;
    s[tid] = v;
    __syncthreads();
    #pragma unroll
    for (int off = 1; off < 256; off <<= 1){
        int t = (tid >= off) ? s[tid - off] : 0;
        __syncthreads();
        s[tid] += t;
        __syncthreads();
    }
    int ex = s[tid] - v + boff[blockIdx.x];
    if (i < N_DSTN){ ptr[i] = ex; cursor[i] = ex; }
}

__global__ void scatter_kernel(const int* __restrict__ src, const int* __restrict__ dst,
                               int* __restrict__ cursor, int* __restrict__ csr){
    int i = blockIdx.x * 256 + threadIdx.x;
    if (i < NE){
        int d = dst[i];
        int pos = atomicAdd(&cursor[d], 1);
        csr[pos] = src[i];
    }
}

// ---- per-dst aggregation, no online max (exp safe here), 4-deep pipeline --
__global__ __launch_bounds__(256) void aggregate_kernel(
        const unsigned short* __restrict__ fs, const unsigned short* __restrict__ fd,
        const unsigned short* __restrict__ res, const float* __restrict__ attn,
        const int* __restrict__ ptr, const int* __restrict__ deg,
        const int* __restrict__ csr, unsigned short* __restrict__ x){
    int wv = threadIdx.x >> 6;
    int d = blockIdx.x * 4 + wv;
    if (d >= N_DSTN) return;
    int lane = threadIdx.x & 63;
    int c4 = lane * 4;
    float4 fdv = ld4b(fd + (size_t)d * 256 + c4);
    float4 at = *reinterpret_cast<const float4*>(attn + (lane >> 4) * 64 + (lane & 15) * 4);
    int p = ptr[d], dg = deg[d];
    float l = 0.f;
    float4 acc = make_float4(0.f, 0.f, 0.f, 0.f);
    for (int base = 0; base < dg; base += 64){
        int cnt = min(64, dg - base);
        int sreg = (lane < cnt) ? csr[p + base + lane] : 0;
        float4 b0 = ld4b(fs + (size_t)__shfl(sreg, 0) * 256 + c4);
        float4 b1 = ld4b(fs + (size_t)__shfl(sreg, 1 & 63) * 256 + c4);
        float4 b2 = ld4b(fs + (size_t)__shfl(sreg, 2 & 63) * 256 + c4);
        float4 b3 = ld4b(fs + (size_t)__shfl(sreg, 3 & 63) * 256 + c4);
        for (int j = 0; j < cnt; j += 4){
            float4 n0 = ld4b(fs + (size_t)__shfl(sreg, (j + 4) & 63) * 256 + c4);
            float4 n1 = ld4b(fs + (size_t)__shfl(sreg, (j + 5) & 63) * 256 + c4);
            float4 n2 = ld4b(fs + (size_t)__shfl(sreg, (j + 6) & 63) * 256 + c4);
            float4 n3 = ld4b(fs + (size_t)__shfl(sreg, (j + 7) & 63) * 256 + c4);
#define PROC(BV, T) { \
            float ex = BV.x + fdv.x; ex = ex > 0.f ? ex : NEG * ex; \
            float ey = BV.y + fdv.y; ey = ey > 0.f ? ey : NEG * ey; \
            float ez = BV.z + fdv.z; ez = ez > 0.f ? ez : NEG * ez; \
            float ew = BV.w + fdv.w; ew = ew > 0.f ? ew : NEG * ew; \
            float part = ex * at.x + ey * at.y + ez * at.z + ew * at.w; \
            part += __shfl_xor(part, 1); \
            part += __shfl_xor(part, 2); \
            part += __shfl_xor(part, 4); \
            part += __shfl_xor(part, 8); \
            float wgt = ((j + (T)) < cnt) ? __expf(part) : 0.f; \
            l += wgt; \
            acc.x = fmaf(wgt, BV.x, acc.x); \
            acc.y = fmaf(wgt, BV.y, acc.y); \
            acc.z = fmaf(wgt, BV.z, acc.z); \
            acc.w = fmaf(wgt, BV.w, acc.w); }
            PROC(b0, 0) PROC(b1, 1) PROC(b2, 2) PROC(b3, 3)
#undef PROC
            b0 = n0; b1 = n1; b2 = n2; b3 = n3;
        }
    }
    float inv = (l > 0.f) ? 1.f / l : 0.f;
    float4 rv = ld4b(res + (size_t)d * 256 + c4);
    float xx = fmaxf(fmaf(acc.x, inv, rv.x), 0.f);
    float xy = fmaxf(fmaf(acc.y, inv, rv.y), 0.f);
    float xz = fmaxf(fmaf(acc.z, inv, rv.z), 0.f);
    float xw = fmaxf(fmaf(acc.w, inv, rv.w), 0.f);
    uint2 o;
    o.x = (unsigned)f2bf(xx) | ((unsigned)f2bf(xy) << 16);
    o.y = (unsigned)f2bf(xz) | ((unsigned)f2bf(xw) << 16);
    *reinterpret_cast<uint2*>(x + (size_t)d * 256 + c4) = o;
}

// ---- GRU v6: 64-row x 256-col blocks, 1024 thr / 16 waves, 1 tile/wave ----
// v5 post-mortem: 2 tiles/wave = 128 acc VGPRs -> compiler capped at 128,
// ~90 regs spilled -> 318 MB scratch writes, MfmaUtil 6%. v6 keeps the
// "stage K=512 once, one barrier" structure but gives each wave exactly ONE
// 32x32 output tile (rt = w>>3, ct = w&7): accs {r,z,nx,nh} = 64 VGPRs,
// total demand ~116 < 128 cap from __launch_bounds__(1024,4) -> no spill.
// LDS: 64 rows x 512 bf16 = 64KB, 16B-chunk XOR swizzle (c ^ (row&7)).
// H0 f32->bf16 converted exactly once per element. Weights stream from L2
// (786KB footprint, fits every XCD's 4MB L2); epilogue H0 rows L2-hot.
__global__ __launch_bounds__(1024, 4) void gru_kernel(
        const unsigned short* __restrict__ Xb,
        const float* __restrict__ H0, const unsigned short* __restrict__ Wf,
        const float* __restrict__ bih, const float* __restrict__ bhh,
        float* __restrict__ outH){
    __shared__ unsigned short As[64 * 512];
    int tid = threadIdx.x;
    int m0 = blockIdx.x << 6;
    // stage X half: 64 rows x 256 bf16 (chunks 0..31, 16B each)
    #pragma unroll
    for (int i = 0; i < 2; ++i){
        int ci = tid + i * 1024;
        int row = ci >> 5, c = ci & 31;
        int gr = m0 + row; if (gr >= N_DSTN) gr = N_DSTN - 1;
        *reinterpret_cast<uint4*>(As + row * 512 + ((c ^ (row & 7)) << 3)) =
            *reinterpret_cast<const uint4*>(Xb + (size_t)gr * 256 + (c << 3));
    }
    // stage H half: 64 rows x 256 f32 -> bf16 (chunks 32..63)
    #pragma unroll
    for (int i = 0; i < 2; ++i){
        int ci = tid + i * 1024;
        int row = ci >> 5, c = ci & 31;
        int gr = m0 + row; if (gr >= N_DSTN) gr = N_DSTN - 1;
        const float* hp = H0 + (size_t)gr * 256 + (c << 3);
        float4 f0 = *reinterpret_cast<const float4*>(hp);
        float4 f1 = *reinterpret_cast<const float4*>(hp + 4);
        uint4 o;
        o.x = (unsigned)f2bf(f0.x) | ((unsigned)f2bf(f0.y) << 16);
        o.y = (unsigned)f2bf(f0.z) | ((unsigned)f2bf(f0.w) << 16);
        o.z = (unsigned)f2bf(f1.x) | ((unsigned)f2bf(f1.y) << 16);
        o.w = (unsigned)f2bf(f1.z) | ((unsigned)f2bf(f1.w) << 16);
        *reinterpret_cast<uint4*>(As + row * 512 + (((c + 32) ^ (row & 7)) << 3)) = o;
    }
    __syncthreads();
    int w = tid >> 6, lane = tid & 63;
    int l31 = lane & 31, half = lane >> 5;
    int rt = w >> 3, ct = w & 7;          // 2 row-tiles x 8 col-tiles
    int arow = rt * 32 + l31;
    int rl = arow & 7;
    const unsigned short* apb = As + arow * 512;
    const unsigned short* br = Wf + (size_t)ct * 16384 + lane * 8;
    const unsigned short* bz = br + 131072;
    const unsigned short* bn = br + 262144;
    float16v zv = {0,0,0,0,0,0,0,0,0,0,0,0,0,0,0,0};
    float16v ar = zv, az = zv, anx = zv, anh = zv;
    // K-part 1: X @ Wih (kk 0..15), n-gate into anx
    #pragma unroll
    for (int kk = 0; kk < 16; ++kk){
        short8 a  = *reinterpret_cast<const short8*>(apb + (((kk * 2 + half) ^ rl) << 3));
        short8 vr = *reinterpret_cast<const short8*>(br + kk * 512);
        short8 vz = *reinterpret_cast<const short8*>(bz + kk * 512);
        short8 vn = *reinterpret_cast<const short8*>(bn + kk * 512);
        ar  = __builtin_amdgcn_mfma_f32_32x32x16_bf16(a, vr, ar,  0, 0, 0);
        az  = __builtin_amdgcn_mfma_f32_32x32x16_bf16(a, vz, az,  0, 0, 0);
        anx = __builtin_amdgcn_mfma_f32_32x32x16_bf16(a, vn, anx, 0, 0, 0);
    }
    // K-part 2: H @ Whh (kk 16..31), n-gate into anh
    #pragma unroll
    for (int kk = 16; kk < 32; ++kk){
        short8 a  = *reinterpret_cast<const short8*>(apb + (((kk * 2 + half) ^ rl) << 3));
        short8 vr = *reinterpret_cast<const short8*>(br + kk * 512);
        short8 vz = *reinterpret_cast<const short8*>(bz + kk * 512);
        short8 vn = *reinterpret_cast<const short8*>(bn + kk * 512);
        ar  = __builtin_amdgcn_mfma_f32_32x32x16_bf16(a, vr, ar,  0, 0, 0);
        az  = __builtin_amdgcn_mfma_f32_32x32x16_bf16(a, vz, az,  0, 0, 0);
        anh = __builtin_amdgcn_mfma_f32_32x32x16_bf16(a, vn, anh, 0, 0, 0);
    }
    // fused GRU epilogue; H0 rows are L2-hot (staged by this block above)
    int cg = ct * 32 + l31;
    float rb = bih[cg] + bhh[cg];
    float zb = bih[256 + cg] + bhh[256 + cg];
    float bin = bih[512 + cg], bhn = bhh[512 + cg];
    #pragma unroll
    for (int r = 0; r < 16; ++r){
        int m = m0 + rt * 32 + (r & 3) + 8 * (r >> 2) + 4 * half;
        if (m < N_DSTN){
            float h0v = H0[(size_t)m * 256 + cg];
            float rrg = 1.f / (1.f + __expf(-(ar[r] + rb)));
            float zg  = 1.f / (1.f + __expf(-(az[r] + zb)));
            float nx = anx[r] + bin + rrg * (anh[r] + bhn);
            float tm = __expf(-2.f * fabsf(nx));
            float nn = (1.f - tm) / (1.f + tm);
            nn = (nx >= 0.f) ? nn : -nn;
            outH[(size_t)m * 256 + cg] = (1.f - zg) * nn + zg * h0v;
        }
    }
}

// ---- logits = h @ W_out + b_out ------------------------------------------
__global__ __launch_bounds__(256) void logits_kernel(
        const float* __restrict__ H, const float* __restrict__ Wout,
        const float* __restrict__ bout, float* __restrict__ outL){
    __shared__ float Hl[16 * 260];
    __shared__ float Wl[16 * 260];
    int tid = threadIdx.x;
    int m0 = blockIdx.x * 16;
    #pragma unroll
    for (int i = 0; i < 4; ++i){
        int ci = tid + i * 256;
        int row = ci >> 6;
        int c4 = (ci & 63) << 2;
        int gr = m0 + row; if (gr >= N_DSTN) gr = N_DSTN - 1;
        float4 v = *reinterpret_cast<const float4*>(H + (size_t)gr * 256 + c4);
        float* dp = Hl + row * 260 + c4;
        dp[0] = v.x; dp[1] = v.y; dp[2] = v.z; dp[3] = v.w;
    }
    #pragma unroll
    for (int i = 0; i < 16; ++i){
        int ci = tid + i * 256;
        int c = ci >> 4, j = ci & 15;
        Wl[j * 260 + c] = Wout[c * 16 + j];
    }
    __syncthreads();
    int row = tid >> 4, j = tid & 15;
    const float* hr = Hl + row * 260;
    const float* wr = Wl + j * 260;
    float acc = bout[j];
    #pragma unroll
    for (int c = 0; c < 256; c += 4){
        float4 hv = *reinterpret_cast<const float4*>(hr + c);
        float4 wv = *reinterpret_cast<const float4*>(wr + c);
        acc = fmaf(hv.x, wv.x, fmaf(hv.y, wv.y, fmaf(hv.z, wv.z, fmaf(hv.w, wv.w, acc))));
    }
    int m = m0 + row;
    if (m < N_DSTN) outL[m * 16 + j] = acc;
}

extern "C" void kernel_launch(void* const* d_in, const int* in_sizes, int n_in,
                              void* d_out, int out_size, void* d_ws, size_t ws_size,
                              hipStream_t stream){
    const float* feat_gt = (const float*)d_in[0];
    const float* feat_ag = (const float*)d_in[1];
    const float* h0      = (const float*)d_in[2];
    const int*   e_src   = (const int*)d_in[3];
    const int*   e_dst   = (const int*)d_in[4];
    const float* W_src   = (const float*)d_in[5];
    const float* b_src   = (const float*)d_in[6];
    const float* W_dst   = (const float*)d_in[7];
    const float* b_dst   = (const float*)d_in[8];
    const float* attn    = (const float*)d_in[9];
    const float* W_res   = (const float*)d_in[10];
    const float* b_res   = (const float*)d_in[11];
    const float* W_ih    = (const float*)d_in[12];
    const float* W_hh    = (const float*)d_in[13];
    const float* b_ih    = (const float*)d_in[14];
    const float* b_hh    = (const float*)d_in[15];
    const float* W_out   = (const float*)d_in[16];
    const float* b_out   = (const float*)d_in[17];

    float* outL = (float*)d_out;
    float* outH = outL + (size_t)N_DSTN * 16;

    char* ws = (char*)d_ws;
    size_t off = 0;
    auto alloc = [&](size_t bytes) -> void* {
        void* p = ws + off; off = (off + bytes + 255) & ~(size_t)255; return p;
    };
    unsigned short* fs   = (unsigned short*)alloc((size_t)N_SRCN * 256 * 2);
    unsigned short* fd   = (unsigned short*)alloc((size_t)N_DSTN * 256 * 2);
    unsigned short* res  = (unsigned short*)alloc((size_t)N_DSTN * 256 * 2);
    unsigned short* xb   = (unsigned short*)alloc((size_t)N_DSTN * 256 * 2);
    unsigned short* Wt2  = (unsigned short*)alloc(49152 * 2);
    unsigned short* Wf   = (unsigned short*)alloc(393216 * 2);
    int* deg    = (int*)alloc(N_DSTN * 4);
    int* ptr    = (int*)alloc(N_DSTN * 4);
    int* cursor = (int*)alloc(N_DSTN * 4);
    int* csr    = (int*)alloc((size_t)NE * 4);
    int* bsum   = (int*)alloc(256 * 4);
    int* boff   = (int*)alloc(256 * 4);

    hipMemsetAsync(deg, 0, N_DSTN * 4, stream);
    pack_kernel<<<1728, 256, 0, stream>>>(W_src, W_dst, W_res, W_ih, W_hh, Wt2, Wf);

    proj_kernel<<<dim3(4, 782, 3), 256, 0, stream>>>(feat_gt, feat_ag, Wt2,
                                                     b_src, b_dst, b_res, fs, fd, res);

    degree_kernel<<<3125, 256, 0, stream>>>(e_dst, deg);
    scan1_kernel<<<196, 256, 0, stream>>>(deg, bsum);
    scan2_kernel<<<1, 256, 0, stream>>>(bsum, boff);
    scan3_kernel<<<196, 256, 0, stream>>>(deg, boff, ptr, cursor);
    scatter_kernel<<<3125, 256, 0, stream>>>(e_src, e_dst, cursor, csr);
    aggregate_kernel<<<12500, 256, 0, stream>>>(fs, fd, res, attn, ptr, deg, csr, xb);

    gru_kernel<<<782, 1024, 0, stream>>>(xb, h0, Wf, b_ih, b_hh, outH);
    logits_kernel<<<3125, 256, 0, stream>>>(outH, W_out, b_out, outL);
}

// Round 3
// 458.497 us; speedup vs baseline: 1.3202x; 1.0616x over previous
//
#include <hip/hip_runtime.h>
#include <stdint.h>

#define N_SRCN 50000
#define N_DSTN 50000
#define NE     800000
#define HIDN   256
#define NEG    0.2f

typedef __attribute__((ext_vector_type(8)))  short short8;
typedef __attribute__((ext_vector_type(16))) float float16v;

__device__ __forceinline__ float bf2f(unsigned short u){
    union { unsigned u32; float f; } c; c.u32 = ((unsigned)u) << 16; return c.f;
}
__device__ __forceinline__ unsigned short f2bf(float f){
    union { float f; unsigned u; } c; c.f = f;
    unsigned r = c.u + 0x7fffu + ((c.u >> 16) & 1u);
    return (unsigned short)(r >> 16);
}
__device__ __forceinline__ float4 ld4b(const unsigned short* p){
    uint2 u = *reinterpret_cast<const uint2*>(p);
    float4 r;
    r.x = bf2f((unsigned short)(u.x & 0xffff));
    r.y = bf2f((unsigned short)(u.x >> 16));
    r.z = bf2f((unsigned short)(u.y & 0xffff));
    r.w = bf2f((unsigned short)(u.y >> 16));
    return r;
}
// async 16B global -> LDS (wave-uniform LDS base + lane*16 dest)
__device__ __forceinline__ void gload_lds16(const unsigned short* g, unsigned short* l){
    __builtin_amdgcn_global_load_lds(
        (const __attribute__((address_space(1))) void*)g,
        (__attribute__((address_space(3))) void*)l,
        16, 0, 0);
}

// ---- pack weights, input-indexed (coalesced reads, scattered 2B writes) ----
// Wt2: [which(3)][cb(8)][kk(4)][lane(64)][8]   (49152)
// Wf : [g(3)][cb(8)][kk(32)][lane(64)][8]      (393216), K=512 = [Wih|Whh]
__global__ void pack_kernel(const float* __restrict__ Wsrc, const float* __restrict__ Wdst,
                            const float* __restrict__ Wres, const float* __restrict__ Wih,
                            const float* __restrict__ Whh,
                            unsigned short* __restrict__ Wt2,
                            unsigned short* __restrict__ Wf){
    int i = blockIdx.x * 256 + threadIdx.x;
    if (i < 49152){
        int which = i >> 14, j = i & 16383;          // j = k*256 + c
        int k = j >> 8, c = j & 255;
        const float* W = (which == 0) ? Wsrc : (which == 1 ? Wdst : Wres);
        float v = W[j];
        int off = which * 16384 + (c >> 5) * 2048 + (k >> 4) * 512
                + (((k >> 3) & 1) * 32 + (c & 31)) * 8 + (k & 7);
        Wt2[off] = f2bf(v);
    } else if (i < 49152 + 196608){
        int o = i - 49152;                            // Wih flat: (g*256+c)*256+k
        int row = o >> 8, k = o & 255;
        int g = row >> 8, c = row & 255;
        float v = Wih[o];
        int off = g * 131072 + (c >> 5) * 16384 + (k >> 4) * 512
                + (((k >> 3) & 1) * 32 + (c & 31)) * 8 + (k & 7);
        Wf[off] = f2bf(v);
    } else if (i < 49152 + 393216){
        int o = i - 49152 - 196608;                   // Whh
        int row = o >> 8, k = o & 255;
        int g = row >> 8, c = row & 255;
        float v = Whh[o];
        int off = g * 131072 + (c >> 5) * 16384 + (16 + (k >> 4)) * 512
                + (((k >> 3) & 1) * 32 + (c & 31)) * 8 + (k & 7);
        Wf[off] = f2bf(v);
    }
}

// ---- fused projection GEMM (K=64), z selects {src, dst, res} --------------
__global__ __launch_bounds__(256) void proj_kernel(
        const float* __restrict__ Agt, const float* __restrict__ Aag,
        const unsigned short* __restrict__ Wt2,
        const float* __restrict__ bsrc, const float* __restrict__ bdst,
        const float* __restrict__ bres,
        unsigned short* __restrict__ fs, unsigned short* __restrict__ fd,
        unsigned short* __restrict__ resb){
    __shared__ unsigned short As[64 * 72];
    __shared__ unsigned short Cs[64 * 72];
    int z = blockIdx.z;
    const float* A = (z == 0) ? Agt : Aag;
    const float* bias = (z == 0) ? bsrc : (z == 1 ? bdst : bres);
    unsigned short* out = (z == 0) ? fs : (z == 1 ? fd : resb);
    const unsigned short* Wb = Wt2 + z * 16384;
    int tid = threadIdx.x;
    int m0 = blockIdx.y * 64;
    #pragma unroll
    for (int i = 0; i < 4; ++i){
        int ci = tid + i * 256;
        int row = ci >> 4;
        int k4 = (ci & 15) << 2;
        int gr = m0 + row; if (gr >= N_SRCN) gr = N_SRCN - 1;
        float4 v = *reinterpret_cast<const float4*>(A + (size_t)gr * 64 + k4);
        unsigned short* dp = As + row * 72 + k4;
        dp[0] = f2bf(v.x); dp[1] = f2bf(v.y); dp[2] = f2bf(v.z); dp[3] = f2bf(v.w);
    }
    __syncthreads();
    int lane = tid & 63, w = tid >> 6;
    int l31 = lane & 31, half = lane >> 5;
    int msub = (w & 1) * 32;
    int cbw = blockIdx.x * 2 + (w >> 1);
    const unsigned short* bb = Wb + cbw * 2048 + lane * 8;
    const unsigned short* ap = As + (msub + l31) * 72 + half * 8;
    float16v acc = {0,0,0,0,0,0,0,0,0,0,0,0,0,0,0,0};
    #pragma unroll
    for (int ks = 0; ks < 4; ++ks){
        short8 a = *reinterpret_cast<const short8*>(ap + ks * 16);
        short8 b = *reinterpret_cast<const short8*>(bb + ks * 512);
        acc = __builtin_amdgcn_mfma_f32_32x32x16_bf16(a, b, acc, 0, 0, 0);
    }
    float bv = bias[cbw * 32 + l31];
    int ccol = (w >> 1) * 32 + l31;
    #pragma unroll
    for (int r = 0; r < 16; ++r){
        int row = (r & 3) + 8 * (r >> 2) + 4 * half + msub;
        Cs[row * 72 + ccol] = f2bf(acc[r] + bv);
    }
    __syncthreads();
    int srow = tid >> 2, chunk = tid & 3;
    int gr2 = m0 + srow;
    if (gr2 < N_SRCN){
        const uint4* sp = reinterpret_cast<const uint4*>(Cs + srow * 72 + chunk * 16);
        uint4* gp = reinterpret_cast<uint4*>(out + (size_t)gr2 * 256 + blockIdx.x * 64 + chunk * 16);
        gp[0] = sp[0];
        gp[1] = sp[1];
    }
}

// ---- edge CSR build -------------------------------------------------------
__global__ void degree_kernel(const int* __restrict__ dst, int* __restrict__ deg){
    int i = blockIdx.x * 256 + threadIdx.x;
    if (i < NE) atomicAdd(&deg[dst[i]], 1);
}

__global__ void scan1_kernel(const int* __restrict__ deg, int* __restrict__ bsum){
    __shared__ int s[256];
    int tid = threadIdx.x;
    int i = blockIdx.x * 256 + tid;
    s[tid] = (i < N_DSTN) ? deg[i] : 0;
    __syncthreads();
    #pragma unroll
    for (int off = 128; off; off >>= 1){
        if (tid < off) s[tid] += s[tid + off];
        __syncthreads();
    }
    if (tid == 0) bsum[blockIdx.x] = s[0];
}

__global__ void scan2_kernel(const int* __restrict__ bsum, int* __restrict__ boff){
    __shared__ int s[256];
    int tid = threadIdx.x;
    int v = (tid < 196) ? bsum[tid] : 0;
    s[tid] = v;
    __syncthreads();
    #pragma unroll
    for (int off = 1; off < 256; off <<= 1){
        int t = (tid >= off) ? s[tid - off] : 0;
        __syncthreads();
        s[tid] += t;
        __syncthreads();
    }
    if (tid < 196) boff[tid] = s[tid] - v;
}

__global__ void scan3_kernel(const int* __restrict__ deg, const int* __restrict__ boff,
                             int* __restrict__ ptr, int* __restrict__ cursor){
    __shared__ int s[256];
    int tid = threadIdx.x;
    int i = blockIdx.x * 256 + tid;
    int v = (i < N_DSTN) ? deg[i] : 0;
    s[tid] = v;
    __syncthreads();
    #pragma unroll
    for (int off = 1; off < 256; off <<= 1){
        int t = (tid >= off) ? s[tid - off] : 0;
        __syncthreads();
        s[tid] += t;
        __syncthreads();
    }
    int ex = s[tid] - v + boff[blockIdx.x];
    if (i < N_DSTN){ ptr[i] = ex; cursor[i] = ex; }
}

__global__ void scatter_kernel(const int* __restrict__ src, const int* __restrict__ dst,
                               int* __restrict__ cursor, int* __restrict__ csr){
    int i = blockIdx.x * 256 + threadIdx.x;
    if (i < NE){
        int d = dst[i];
        int pos = atomicAdd(&cursor[d], 1);
        csr[pos] = src[i];
    }
}

// ---- per-dst aggregation, no online max (exp safe here), 4-deep pipeline --
__global__ __launch_bounds__(256) void aggregate_kernel(
        const unsigned short* __restrict__ fs, const unsigned short* __restrict__ fd,
        const unsigned short* __restrict__ res, const float* __restrict__ attn,
        const int* __restrict__ ptr, const int* __restrict__ deg,
        const int* __restrict__ csr, unsigned short* __restrict__ x){
    int wv = threadIdx.x >> 6;
    int d = blockIdx.x * 4 + wv;
    if (d >= N_DSTN) return;
    int lane = threadIdx.x & 63;
    int c4 = lane * 4;
    float4 fdv = ld4b(fd + (size_t)d * 256 + c4);
    float4 at = *reinterpret_cast<const float4*>(attn + (lane >> 4) * 64 + (lane & 15) * 4);
    int p = ptr[d], dg = deg[d];
    float l = 0.f;
    float4 acc = make_float4(0.f, 0.f, 0.f, 0.f);
    for (int base = 0; base < dg; base += 64){
        int cnt = min(64, dg - base);
        int sreg = (lane < cnt) ? csr[p + base + lane] : 0;
        float4 b0 = ld4b(fs + (size_t)__shfl(sreg, 0) * 256 + c4);
        float4 b1 = ld4b(fs + (size_t)__shfl(sreg, 1 & 63) * 256 + c4);
        float4 b2 = ld4b(fs + (size_t)__shfl(sreg, 2 & 63) * 256 + c4);
        float4 b3 = ld4b(fs + (size_t)__shfl(sreg, 3 & 63) * 256 + c4);
        for (int j = 0; j < cnt; j += 4){
            float4 n0 = ld4b(fs + (size_t)__shfl(sreg, (j + 4) & 63) * 256 + c4);
            float4 n1 = ld4b(fs + (size_t)__shfl(sreg, (j + 5) & 63) * 256 + c4);
            float4 n2 = ld4b(fs + (size_t)__shfl(sreg, (j + 6) & 63) * 256 + c4);
            float4 n3 = ld4b(fs + (size_t)__shfl(sreg, (j + 7) & 63) * 256 + c4);
#define PROC(BV, T) { \
            float ex = BV.x + fdv.x; ex = ex > 0.f ? ex : NEG * ex; \
            float ey = BV.y + fdv.y; ey = ey > 0.f ? ey : NEG * ey; \
            float ez = BV.z + fdv.z; ez = ez > 0.f ? ez : NEG * ez; \
            float ew = BV.w + fdv.w; ew = ew > 0.f ? ew : NEG * ew; \
            float part = ex * at.x + ey * at.y + ez * at.z + ew * at.w; \
            part += __shfl_xor(part, 1); \
            part += __shfl_xor(part, 2); \
            part += __shfl_xor(part, 4); \
            part += __shfl_xor(part, 8); \
            float wgt = ((j + (T)) < cnt) ? __expf(part) : 0.f; \
            l += wgt; \
            acc.x = fmaf(wgt, BV.x, acc.x); \
            acc.y = fmaf(wgt, BV.y, acc.y); \
            acc.z = fmaf(wgt, BV.z, acc.z); \
            acc.w = fmaf(wgt, BV.w, acc.w); }
            PROC(b0, 0) PROC(b1, 1) PROC(b2, 2) PROC(b3, 3)
#undef PROC
            b0 = n0; b1 = n1; b2 = n2; b3 = n3;
        }
    }
    float inv = (l > 0.f) ? 1.f / l : 0.f;
    float4 rv = ld4b(res + (size_t)d * 256 + c4);
    float xx = fmaxf(fmaf(acc.x, inv, rv.x), 0.f);
    float xy = fmaxf(fmaf(acc.y, inv, rv.y), 0.f);
    float xz = fmaxf(fmaf(acc.z, inv, rv.z), 0.f);
    float xw = fmaxf(fmaf(acc.w, inv, rv.w), 0.f);
    uint2 o;
    o.x = (unsigned)f2bf(xx) | ((unsigned)f2bf(xy) << 16);
    o.y = (unsigned)f2bf(xz) | ((unsigned)f2bf(xw) << 16);
    *reinterpret_cast<uint2*>(x + (size_t)d * 256 + c4) = o;
}

// ---- GRU v7: B-stream through LDS, 2-phase global_load_lds double-buffer --
// v6 post-mortem: 16-wave block @ 1 blk/CU -> 128 unified regs/wave; 64 AGPR
// accs left only 64 VGPR -> no prefetch depth -> latency-bound on per-wave
// global weight loads (MfmaUtil 10%). v7 stages the weight K-slices into
// SHARED LDS with async global_load_lds (no VGPR round-trip, issued one
// phase ahead; __syncthreads' implicit vmcnt(0) drain lands after compute).
// LDS: A 64x512 bf16 = 64KB (staged once, X|H) + B dbuf 2 x 24KB = 112KB.
// Per phase (K=16): per wave 1 A ds_read + 3 B ds_reads (contiguous 1KB/wave,
// conflict-free) + 3 MFMAs. Regs: 48 AGPR accs + ~50 VGPR < 128 cap.
__global__ __launch_bounds__(1024, 4) void gru_kernel(
        const unsigned short* __restrict__ Xb,
        const float* __restrict__ H0, const unsigned short* __restrict__ Wf,
        const float* __restrict__ bih, const float* __restrict__ bhh,
        float* __restrict__ outH){
    __shared__ unsigned short As[64 * 512];
    __shared__ unsigned short Bs[2 * 12288];
    int tid = threadIdx.x;
    int m0 = blockIdx.x << 6;
    int w = tid >> 6, lane = tid & 63;
    // stage X half: 64 rows x 256 bf16 (chunks 0..31, 16B each, XOR swizzle)
    #pragma unroll
    for (int i = 0; i < 2; ++i){
        int ci = tid + i * 1024;
        int row = ci >> 5, c = ci & 31;
        int gr = m0 + row; if (gr >= N_DSTN) gr = N_DSTN - 1;
        *reinterpret_cast<uint4*>(As + row * 512 + ((c ^ (row & 7)) << 3)) =
            *reinterpret_cast<const uint4*>(Xb + (size_t)gr * 256 + (c << 3));
    }
    // stage H half: 64 rows x 256 f32 -> bf16 (chunks 32..63)
    #pragma unroll
    for (int i = 0; i < 2; ++i){
        int ci = tid + i * 1024;
        int row = ci >> 5, c = ci & 31;
        int gr = m0 + row; if (gr >= N_DSTN) gr = N_DSTN - 1;
        const float* hp = H0 + (size_t)gr * 256 + (c << 3);
        float4 f0 = *reinterpret_cast<const float4*>(hp);
        float4 f1 = *reinterpret_cast<const float4*>(hp + 4);
        uint4 o;
        o.x = (unsigned)f2bf(f0.x) | ((unsigned)f2bf(f0.y) << 16);
        o.y = (unsigned)f2bf(f0.z) | ((unsigned)f2bf(f0.w) << 16);
        o.z = (unsigned)f2bf(f1.x) | ((unsigned)f2bf(f1.y) << 16);
        o.w = (unsigned)f2bf(f1.z) | ((unsigned)f2bf(f1.w) << 16);
        *reinterpret_cast<uint4*>(As + row * 512 + (((c + 32) ^ (row & 7)) << 3)) = o;
    }
    // B prologue: stage phase 0 slice (kk=0: 3 gates x 8 cb x 64 lanes x 16B)
    {
        int g = w >> 3, cb = w & 7;
        gload_lds16(Wf + g * 131072 + cb * 16384 + lane * 8, Bs + w * 512);
        if (w < 8)
            gload_lds16(Wf + 2 * 131072 + w * 16384 + lane * 8, Bs + (16 + w) * 512);
    }
    __syncthreads();   // drains lgkmcnt (A ds_writes) + vmcnt (B loads)

    int l31 = lane & 31, half = lane >> 5;
    int rt = w >> 3, ct = w & 7;          // 2 row-tiles x 8 col-tiles
    int arow = rt * 32 + l31;
    int rl = arow & 7;
    const unsigned short* apb = As + arow * 512;
    int sg = w >> 3, scb = w & 7;          // staging roles
    float16v zv = {0,0,0,0,0,0,0,0,0,0,0,0,0,0,0,0};
    float16v ar = zv, az = zv, anx = zv, anh = zv;
    #pragma unroll 2
    for (int p = 0; p < 32; ++p){
        // issue stage for phase p+1 into the other buffer (async, drained by
        // the __syncthreads at the end of this iteration)
        if (p + 1 < 32){
            unsigned short* db = Bs + ((p + 1) & 1) * 12288;
            gload_lds16(Wf + sg * 131072 + scb * 16384 + (p + 1) * 512 + lane * 8,
                        db + w * 512);
            if (w < 8)
                gload_lds16(Wf + 2 * 131072 + w * 16384 + (p + 1) * 512 + lane * 8,
                            db + (16 + w) * 512);
        }
        // compute phase p from current buffer
        const unsigned short* bp = Bs + (p & 1) * 12288;
        short8 a  = *reinterpret_cast<const short8*>(apb + (((p * 2 + half) ^ rl) << 3));
        short8 vr = *reinterpret_cast<const short8*>(bp + (0 * 8 + ct) * 512 + lane * 8);
        short8 vz = *reinterpret_cast<const short8*>(bp + (1 * 8 + ct) * 512 + lane * 8);
        short8 vn = *reinterpret_cast<const short8*>(bp + (2 * 8 + ct) * 512 + lane * 8);
        ar = __builtin_amdgcn_mfma_f32_32x32x16_bf16(a, vr, ar, 0, 0, 0);
        az = __builtin_amdgcn_mfma_f32_32x32x16_bf16(a, vz, az, 0, 0, 0);
        if (p < 16) anx = __builtin_amdgcn_mfma_f32_32x32x16_bf16(a, vn, anx, 0, 0, 0);
        else        anh = __builtin_amdgcn_mfma_f32_32x32x16_bf16(a, vn, anh, 0, 0, 0);
        __syncthreads();  // drains this wave's stage loads + fences buffer swap
    }
    // fused GRU epilogue; H0 rows are L2-hot (staged by this block above)
    int cg = ct * 32 + l31;
    float rb = bih[cg] + bhh[cg];
    float zb = bih[256 + cg] + bhh[256 + cg];
    float bin = bih[512 + cg], bhn = bhh[512 + cg];
    #pragma unroll
    for (int r = 0; r < 16; ++r){
        int m = m0 + rt * 32 + (r & 3) + 8 * (r >> 2) + 4 * half;
        if (m < N_DSTN){
            float h0v = H0[(size_t)m * 256 + cg];
            float rrg = 1.f / (1.f + __expf(-(ar[r] + rb)));
            float zg  = 1.f / (1.f + __expf(-(az[r] + zb)));
            float nx = anx[r] + bin + rrg * (anh[r] + bhn);
            float tm = __expf(-2.f * fabsf(nx));
            float nn = (1.f - tm) / (1.f + tm);
            nn = (nx >= 0.f) ? nn : -nn;
            outH[(size_t)m * 256 + cg] = (1.f - zg) * nn + zg * h0v;
        }
    }
}

// ---- logits = h @ W_out + b_out ------------------------------------------
__global__ __launch_bounds__(256) void logits_kernel(
        const float* __restrict__ H, const float* __restrict__ Wout,
        const float* __restrict__ bout, float* __restrict__ outL){
    __shared__ float Hl[16 * 260];
    __shared__ float Wl[16 * 260];
    int tid = threadIdx.x;
    int m0 = blockIdx.x * 16;
    #pragma unroll
    for (int i = 0; i < 4; ++i){
        int ci = tid + i * 256;
        int row = ci >> 6;
        int c4 = (ci & 63) << 2;
        int gr = m0 + row; if (gr >= N_DSTN) gr = N_DSTN - 1;
        float4 v = *reinterpret_cast<const float4*>(H + (size_t)gr * 256 + c4);
        float* dp = Hl + row * 260 + c4;
        dp[0] = v.x; dp[1] = v.y; dp[2] = v.z; dp[3] = v.w;
    }
    #pragma unroll
    for (int i = 0; i < 16; ++i){
        int ci = tid + i * 256;
        int c = ci >> 4, j = ci & 15;
        Wl[j * 260 + c] = Wout[c * 16 + j];
    }
    __syncthreads();
    int row = tid >> 4, j = tid & 15;
    const float* hr = Hl + row * 260;
    const float* wr = Wl + j * 260;
    float acc = bout[j];
    #pragma unroll
    for (int c = 0; c < 256; c += 4){
        float4 hv = *reinterpret_cast<const float4*>(hr + c);
        float4 wv = *reinterpret_cast<const float4*>(wr + c);
        acc = fmaf(hv.x, wv.x, fmaf(hv.y, wv.y, fmaf(hv.z, wv.z, fmaf(hv.w, wv.w, acc))));
    }
    int m = m0 + row;
    if (m < N_DSTN) outL[m * 16 + j] = acc;
}

extern "C" void kernel_launch(void* const* d_in, const int* in_sizes, int n_in,
                              void* d_out, int out_size, void* d_ws, size_t ws_size,
                              hipStream_t stream){
    const float* feat_gt = (const float*)d_in[0];
    const float* feat_ag = (const float*)d_in[1];
    const float* h0      = (const float*)d_in[2];
    const int*   e_src   = (const int*)d_in[3];
    const int*   e_dst   = (const int*)d_in[4];
    const float* W_src   = (const float*)d_in[5];
    const float* b_src   = (const float*)d_in[6];
    const float* W_dst   = (const float*)d_in[7];
    const float* b_dst   = (const float*)d_in[8];
    const float* attn    = (const float*)d_in[9];
    const float* W_res   = (const float*)d_in[10];
    const float* b_res   = (const float*)d_in[11];
    const float* W_ih    = (const float*)d_in[12];
    const float* W_hh    = (const float*)d_in[13];
    const float* b_ih    = (const float*)d_in[14];
    const float* b_hh    = (const float*)d_in[15];
    const float* W_out   = (const float*)d_in[16];
    const float* b_out   = (const float*)d_in[17];

    float* outL = (float*)d_out;
    float* outH = outL + (size_t)N_DSTN * 16;

    char* ws = (char*)d_ws;
    size_t off = 0;
    auto alloc = [&](size_t bytes) -> void* {
        void* p = ws + off; off = (off + bytes + 255) & ~(size_t)255; return p;
    };
    unsigned short* fs   = (unsigned short*)alloc((size_t)N_SRCN * 256 * 2);
    unsigned short* fd   = (unsigned short*)alloc((size_t)N_DSTN * 256 * 2);
    unsigned short* res  = (unsigned short*)alloc((size_t)N_DSTN * 256 * 2);
    unsigned short* xb   = (unsigned short*)alloc((size_t)N_DSTN * 256 * 2);
    unsigned short* Wt2  = (unsigned short*)alloc(49152 * 2);
    unsigned short* Wf   = (unsigned short*)alloc(393216 * 2);
    int* deg    = (int*)alloc(N_DSTN * 4);
    int* ptr    = (int*)alloc(N_DSTN * 4);
    int* cursor = (int*)alloc(N_DSTN * 4);
    int* csr    = (int*)alloc((size_t)NE * 4);
    int* bsum   = (int*)alloc(256 * 4);
    int* boff   = (int*)alloc(256 * 4);

    hipMemsetAsync(deg, 0, N_DSTN * 4, stream);
    pack_kernel<<<1728, 256, 0, stream>>>(W_src, W_dst, W_res, W_ih, W_hh, Wt2, Wf);

    proj_kernel<<<dim3(4, 782, 3), 256, 0, stream>>>(feat_gt, feat_ag, Wt2,
                                                     b_src, b_dst, b_res, fs, fd, res);

    degree_kernel<<<3125, 256, 0, stream>>>(e_dst, deg);
    scan1_kernel<<<196, 256, 0, stream>>>(deg, bsum);
    scan2_kernel<<<1, 256, 0, stream>>>(bsum, boff);
    scan3_kernel<<<196, 256, 0, stream>>>(deg, boff, ptr, cursor);
    scatter_kernel<<<3125, 256, 0, stream>>>(e_src, e_dst, cursor, csr);
    aggregate_kernel<<<12500, 256, 0, stream>>>(fs, fd, res, attn, ptr, deg, csr, xb);

    gru_kernel<<<782, 1024, 0, stream>>>(xb, h0, Wf, b_ih, b_hh, outH);
    logits_kernel<<<3125, 256, 0, stream>>>(outH, W_out, b_out, outL);
}

// Round 4
// 451.969 us; speedup vs baseline: 1.3393x; 1.0144x over previous
//
#include <hip/hip_runtime.h>
#include <stdint.h>

#define N_SRCN 50000
#define N_DSTN 50000
#define NE     800000
#define HIDN   256
#define NEG    0.2f

typedef __attribute__((ext_vector_type(8)))  short short8;
typedef __attribute__((ext_vector_type(16))) float float16v;

__device__ __forceinline__ float bf2f(unsigned short u){
    union { unsigned u32; float f; } c; c.u32 = ((unsigned)u) << 16; return c.f;
}
__device__ __forceinline__ unsigned short f2bf(float f){
    union { float f; unsigned u; } c; c.f = f;
    unsigned r = c.u + 0x7fffu + ((c.u >> 16) & 1u);
    return (unsigned short)(r >> 16);
}
__device__ __forceinline__ float4 ld4b(const unsigned short* p){
    uint2 u = *reinterpret_cast<const uint2*>(p);
    float4 r;
    r.x = bf2f((unsigned short)(u.x & 0xffff));
    r.y = bf2f((unsigned short)(u.x >> 16));
    r.z = bf2f((unsigned short)(u.y & 0xffff));
    r.w = bf2f((unsigned short)(u.y >> 16));
    return r;
}
// async 16B global -> LDS (wave-uniform LDS base + lane*16 dest)
__device__ __forceinline__ void gload_lds16(const unsigned short* g, unsigned short* l){
    __builtin_amdgcn_global_load_lds(
        (const __attribute__((address_space(1))) void*)g,
        (__attribute__((address_space(3))) void*)l,
        16, 0, 0);
}

// ---- pack weights, input-indexed (coalesced reads, scattered 2B writes) ----
// Wt2: [which(3)][cb(8)][kk(4)][lane(64)][8]   (49152)
// Wf : [g(3)][cb(8)][kk(32)][lane(64)][8]      (393216), K=512 = [Wih|Whh]
__global__ void pack_kernel(const float* __restrict__ Wsrc, const float* __restrict__ Wdst,
                            const float* __restrict__ Wres, const float* __restrict__ Wih,
                            const float* __restrict__ Whh,
                            unsigned short* __restrict__ Wt2,
                            unsigned short* __restrict__ Wf){
    int i = blockIdx.x * 256 + threadIdx.x;
    if (i < 49152){
        int which = i >> 14, j = i & 16383;          // j = k*256 + c
        int k = j >> 8, c = j & 255;
        const float* W = (which == 0) ? Wsrc : (which == 1 ? Wdst : Wres);
        float v = W[j];
        int off = which * 16384 + (c >> 5) * 2048 + (k >> 4) * 512
                + (((k >> 3) & 1) * 32 + (c & 31)) * 8 + (k & 7);
        Wt2[off] = f2bf(v);
    } else if (i < 49152 + 196608){
        int o = i - 49152;                            // Wih flat: (g*256+c)*256+k
        int row = o >> 8, k = o & 255;
        int g = row >> 8, c = row & 255;
        float v = Wih[o];
        int off = g * 131072 + (c >> 5) * 16384 + (k >> 4) * 512
                + (((k >> 3) & 1) * 32 + (c & 31)) * 8 + (k & 7);
        Wf[off] = f2bf(v);
    } else if (i < 49152 + 393216){
        int o = i - 49152 - 196608;                   // Whh
        int row = o >> 8, k = o & 255;
        int g = row >> 8, c = row & 255;
        float v = Whh[o];
        int off = g * 131072 + (c >> 5) * 16384 + (16 + (k >> 4)) * 512
                + (((k >> 3) & 1) * 32 + (c & 31)) * 8 + (k & 7);
        Wf[off] = f2bf(v);
    }
}

// ---- fused projection GEMM (K=64), z selects {src, dst, res} --------------
__global__ __launch_bounds__(256) void proj_kernel(
        const float* __restrict__ Agt, const float* __restrict__ Aag,
        const unsigned short* __restrict__ Wt2,
        const float* __restrict__ bsrc, const float* __restrict__ bdst,
        const float* __restrict__ bres,
        unsigned short* __restrict__ fs, unsigned short* __restrict__ fd,
        unsigned short* __restrict__ resb){
    __shared__ unsigned short As[64 * 72];
    __shared__ unsigned short Cs[64 * 72];
    int z = blockIdx.z;
    const float* A = (z == 0) ? Agt : Aag;
    const float* bias = (z == 0) ? bsrc : (z == 1 ? bdst : bres);
    unsigned short* out = (z == 0) ? fs : (z == 1 ? fd : resb);
    const unsigned short* Wb = Wt2 + z * 16384;
    int tid = threadIdx.x;
    int m0 = blockIdx.y * 64;
    #pragma unroll
    for (int i = 0; i < 4; ++i){
        int ci = tid + i * 256;
        int row = ci >> 4;
        int k4 = (ci & 15) << 2;
        int gr = m0 + row; if (gr >= N_SRCN) gr = N_SRCN - 1;
        float4 v = *reinterpret_cast<const float4*>(A + (size_t)gr * 64 + k4);
        unsigned short* dp = As + row * 72 + k4;
        dp[0] = f2bf(v.x); dp[1] = f2bf(v.y); dp[2] = f2bf(v.z); dp[3] = f2bf(v.w);
    }
    __syncthreads();
    int lane = tid & 63, w = tid >> 6;
    int l31 = lane & 31, half = lane >> 5;
    int msub = (w & 1) * 32;
    int cbw = blockIdx.x * 2 + (w >> 1);
    const unsigned short* bb = Wb + cbw * 2048 + lane * 8;
    const unsigned short* ap = As + (msub + l31) * 72 + half * 8;
    float16v acc = {0,0,0,0,0,0,0,0,0,0,0,0,0,0,0,0};
    #pragma unroll
    for (int ks = 0; ks < 4; ++ks){
        short8 a = *reinterpret_cast<const short8*>(ap + ks * 16);
        short8 b = *reinterpret_cast<const short8*>(bb + ks * 512);
        acc = __builtin_amdgcn_mfma_f32_32x32x16_bf16(a, b, acc, 0, 0, 0);
    }
    float bv = bias[cbw * 32 + l31];
    int ccol = (w >> 1) * 32 + l31;
    #pragma unroll
    for (int r = 0; r < 16; ++r){
        int row = (r & 3) + 8 * (r >> 2) + 4 * half + msub;
        Cs[row * 72 + ccol] = f2bf(acc[r] + bv);
    }
    __syncthreads();
    int srow = tid >> 2, chunk = tid & 3;
    int gr2 = m0 + srow;
    if (gr2 < N_SRCN){
        const uint4* sp = reinterpret_cast<const uint4*>(Cs + srow * 72 + chunk * 16);
        uint4* gp = reinterpret_cast<uint4*>(out + (size_t)gr2 * 256 + blockIdx.x * 64 + chunk * 16);
        gp[0] = sp[0];
        gp[1] = sp[1];
    }
}

// ---- edge CSR build -------------------------------------------------------
__global__ void degree_kernel(const int* __restrict__ dst, int* __restrict__ deg){
    int i = blockIdx.x * 256 + threadIdx.x;
    if (i < NE) atomicAdd(&deg[dst[i]], 1);
}

__global__ void scan1_kernel(const int* __restrict__ deg, int* __restrict__ bsum){
    __shared__ int s[256];
    int tid = threadIdx.x;
    int i = blockIdx.x * 256 + tid;
    s[tid] = (i < N_DSTN) ? deg[i] : 0;
    __syncthreads();
    #pragma unroll
    for (int off = 128; off; off >>= 1){
        if (tid < off) s[tid] += s[tid + off];
        __syncthreads();
    }
    if (tid == 0) bsum[blockIdx.x] = s[0];
}

__global__ void scan2_kernel(const int* __restrict__ bsum, int* __restrict__ boff){
    __shared__ int s[256];
    int tid = threadIdx.x;
    int v = (tid < 196) ? bsum[tid] : 0;
    s[tid] = v;
    __syncthreads();
    #pragma unroll
    for (int off = 1; off < 256; off <<= 1){
        int t = (tid >= off) ? s[tid - off] : 0;
        __syncthreads();
        s[tid] += t;
        __syncthreads();
    }
    if (tid < 196) boff[tid] = s[tid] - v;
}

__global__ void scan3_kernel(const int* __restrict__ deg, const int* __restrict__ boff,
                             int* __restrict__ ptr, int* __restrict__ cursor){
    __shared__ int s[256];
    int tid = threadIdx.x;
    int i = blockIdx.x * 256 + tid;
    int v = (i < N_DSTN) ? deg[i] : 0;
    s[tid] = v;
    __syncthreads();
    #pragma unroll
    for (int off = 1; off < 256; off <<= 1){
        int t = (tid >= off) ? s[tid - off] : 0;
        __syncthreads();
        s[tid] += t;
        __syncthreads();
    }
    int ex = s[tid] - v + boff[blockIdx.x];
    if (i < N_DSTN){ ptr[i] = ex; cursor[i] = ex; }
}

__global__ void scatter_kernel(const int* __restrict__ src, const int* __restrict__ dst,
                               int* __restrict__ cursor, int* __restrict__ csr){
    int i = blockIdx.x * 256 + threadIdx.x;
    if (i < NE){
        int d = dst[i];
        int pos = atomicAdd(&cursor[d], 1);
        csr[pos] = src[i];
    }
}

// ---- per-dst aggregation, no online max (exp safe here), 4-deep pipeline --
__global__ __launch_bounds__(256) void aggregate_kernel(
        const unsigned short* __restrict__ fs, const unsigned short* __restrict__ fd,
        const unsigned short* __restrict__ res, const float* __restrict__ attn,
        const int* __restrict__ ptr, const int* __restrict__ deg,
        const int* __restrict__ csr, unsigned short* __restrict__ x){
    int wv = threadIdx.x >> 6;
    int d = blockIdx.x * 4 + wv;
    if (d >= N_DSTN) return;
    int lane = threadIdx.x & 63;
    int c4 = lane * 4;
    float4 fdv = ld4b(fd + (size_t)d * 256 + c4);
    float4 at = *reinterpret_cast<const float4*>(attn + (lane >> 4) * 64 + (lane & 15) * 4);
    int p = ptr[d], dg = deg[d];
    float l = 0.f;
    float4 acc = make_float4(0.f, 0.f, 0.f, 0.f);
    for (int base = 0; base < dg; base += 64){
        int cnt = min(64, dg - base);
        int sreg = (lane < cnt) ? csr[p + base + lane] : 0;
        float4 b0 = ld4b(fs + (size_t)__shfl(sreg, 0) * 256 + c4);
        float4 b1 = ld4b(fs + (size_t)__shfl(sreg, 1 & 63) * 256 + c4);
        float4 b2 = ld4b(fs + (size_t)__shfl(sreg, 2 & 63) * 256 + c4);
        float4 b3 = ld4b(fs + (size_t)__shfl(sreg, 3 & 63) * 256 + c4);
        for (int j = 0; j < cnt; j += 4){
            float4 n0 = ld4b(fs + (size_t)__shfl(sreg, (j + 4) & 63) * 256 + c4);
            float4 n1 = ld4b(fs + (size_t)__shfl(sreg, (j + 5) & 63) * 256 + c4);
            float4 n2 = ld4b(fs + (size_t)__shfl(sreg, (j + 6) & 63) * 256 + c4);
            float4 n3 = ld4b(fs + (size_t)__shfl(sreg, (j + 7) & 63) * 256 + c4);
#define PROC(BV, T) { \
            float ex = BV.x + fdv.x; ex = ex > 0.f ? ex : NEG * ex; \
            float ey = BV.y + fdv.y; ey = ey > 0.f ? ey : NEG * ey; \
            float ez = BV.z + fdv.z; ez = ez > 0.f ? ez : NEG * ez; \
            float ew = BV.w + fdv.w; ew = ew > 0.f ? ew : NEG * ew; \
            float part = ex * at.x + ey * at.y + ez * at.z + ew * at.w; \
            part += __shfl_xor(part, 1); \
            part += __shfl_xor(part, 2); \
            part += __shfl_xor(part, 4); \
            part += __shfl_xor(part, 8); \
            float wgt = ((j + (T)) < cnt) ? __expf(part) : 0.f; \
            l += wgt; \
            acc.x = fmaf(wgt, BV.x, acc.x); \
            acc.y = fmaf(wgt, BV.y, acc.y); \
            acc.z = fmaf(wgt, BV.z, acc.z); \
            acc.w = fmaf(wgt, BV.w, acc.w); }
            PROC(b0, 0) PROC(b1, 1) PROC(b2, 2) PROC(b3, 3)
#undef PROC
            b0 = n0; b1 = n1; b2 = n2; b3 = n3;
        }
    }
    float inv = (l > 0.f) ? 1.f / l : 0.f;
    float4 rv = ld4b(res + (size_t)d * 256 + c4);
    float xx = fmaxf(fmaf(acc.x, inv, rv.x), 0.f);
    float xy = fmaxf(fmaf(acc.y, inv, rv.y), 0.f);
    float xz = fmaxf(fmaf(acc.z, inv, rv.z), 0.f);
    float xw = fmaxf(fmaf(acc.w, inv, rv.w), 0.f);
    uint2 o;
    o.x = (unsigned)f2bf(xx) | ((unsigned)f2bf(xy) << 16);
    o.y = (unsigned)f2bf(xz) | ((unsigned)f2bf(xw) << 16);
    *reinterpret_cast<uint2*>(x + (size_t)d * 256 + c4) = o;
}

// ---- GRU v8: counted-vmcnt 3-buffer pipeline (T3+T4), raw s_barrier -------
// v7 post-mortem: __syncthreads per phase drains vmcnt(0) -> the "prefetch"
// had ZERO overlap; every phase paid full L2 latency serially (124us, 87%
// stall). v8: triple-buffered B slices, raw s_barrier + counted
// s_waitcnt vmcnt(2) (drain-0 only at tail), stage issued 2 phases ahead
// AFTER the barrier (so the buffer being overwritten -- last read 3 phases
// ago -- is provably drained). 12 waves stage 2x1KB slices each (uniform
// in-flight count); waves 12-15 stage nothing and skip the vmcnt wait.
// A-tile XOR mask widened to &15: 4-way -> 2-way (free) bank aliasing.
// setprio(1) around MFMA cluster (T5, valid now that schedule is phase-split).
// LDS: A 64KB + B 3x24KB = 136KB.
__global__ __launch_bounds__(1024, 4) void gru_kernel(
        const unsigned short* __restrict__ Xb,
        const float* __restrict__ H0, const unsigned short* __restrict__ Wf,
        const float* __restrict__ bih, const float* __restrict__ bhh,
        float* __restrict__ outH){
    __shared__ unsigned short As[64 * 512];
    __shared__ unsigned short Bs[3 * 12288];
    int tid = threadIdx.x;
    int m0 = blockIdx.x << 6;
    int w = tid >> 6, lane = tid & 63;
    // stage X half: 64 rows x 256 bf16 (chunks 0..31, 16B each, XOR &15)
    #pragma unroll
    for (int i = 0; i < 2; ++i){
        int ci = tid + i * 1024;
        int row = ci >> 5, c = ci & 31;
        int gr = m0 + row; if (gr >= N_DSTN) gr = N_DSTN - 1;
        *reinterpret_cast<uint4*>(As + row * 512 + ((c ^ (row & 15)) << 3)) =
            *reinterpret_cast<const uint4*>(Xb + (size_t)gr * 256 + (c << 3));
    }
    // stage H half: 64 rows x 256 f32 -> bf16 (chunks 32..63)
    #pragma unroll
    for (int i = 0; i < 2; ++i){
        int ci = tid + i * 1024;
        int row = ci >> 5, c = ci & 31;
        int gr = m0 + row; if (gr >= N_DSTN) gr = N_DSTN - 1;
        const float* hp = H0 + (size_t)gr * 256 + (c << 3);
        float4 f0 = *reinterpret_cast<const float4*>(hp);
        float4 f1 = *reinterpret_cast<const float4*>(hp + 4);
        uint4 o;
        o.x = (unsigned)f2bf(f0.x) | ((unsigned)f2bf(f0.y) << 16);
        o.y = (unsigned)f2bf(f0.z) | ((unsigned)f2bf(f0.w) << 16);
        o.z = (unsigned)f2bf(f1.x) | ((unsigned)f2bf(f1.y) << 16);
        o.w = (unsigned)f2bf(f1.z) | ((unsigned)f2bf(f1.w) << 16);
        *reinterpret_cast<uint4*>(As + row * 512 + (((c + 32) ^ (row & 15)) << 3)) = o;
    }
    __syncthreads();   // A tile visible to all; drains everything once

    // staging role: wave w < 12 stages slices 2w, 2w+1 of 24 (s -> g=s>>3, cb=s&7)
    int s0 = 2 * w, s1 = 2 * w + 1;
    const unsigned short* g0 = Wf + (s0 >> 3) * 131072 + (s0 & 7) * 16384 + lane * 8;
    const unsigned short* g1 = Wf + (s1 >> 3) * 131072 + (s1 & 7) * 16384 + lane * 8;
    // prologue: issue phase 0 and phase 1 slices
    if (w < 12){
        gload_lds16(g0,       Bs + s0 * 512);
        gload_lds16(g1,       Bs + s1 * 512);
        gload_lds16(g0 + 512, Bs + 12288 + s0 * 512);
        gload_lds16(g1 + 512, Bs + 12288 + s1 * 512);
    }

    int l31 = lane & 31, half = lane >> 5;
    int rt = w >> 3, ct = w & 7;          // 2 row-tiles x 8 col-tiles
    int arow = rt * 32 + l31;
    int rl = arow & 15;
    const unsigned short* apb = As + arow * 512;
    float16v zv = {0,0,0,0,0,0,0,0,0,0,0,0,0,0,0,0};
    float16v ar = zv, az = zv, anx = zv, anh = zv;
    #pragma unroll
    for (int p = 0; p < 32; ++p){
        // wait for phase p's loads (2 per staging wave may stay in flight)
        if (w < 12){
            if (p >= 31) asm volatile("s_waitcnt vmcnt(0)" ::: "memory");
            else         asm volatile("s_waitcnt vmcnt(2)" ::: "memory");
        }
        __builtin_amdgcn_s_barrier();      // all waves' p-loads now complete
        __builtin_amdgcn_sched_barrier(0); // no hoisting across the barrier
        // issue stage for phase p+2 (buffer (p+2)%3 was read in phase p-1,
        // fully drained by the barrier chain)
        if (p + 2 < 32 && w < 12){
            unsigned short* db = Bs + ((p + 2) % 3) * 12288;
            gload_lds16(g0 + (p + 2) * 512, db + s0 * 512);
            gload_lds16(g1 + (p + 2) * 512, db + s1 * 512);
        }
        // compute phase p
        const unsigned short* bp = Bs + (p % 3) * 12288;
        short8 a  = *reinterpret_cast<const short8*>(apb + (((p * 2 + half) ^ rl) << 3));
        short8 vr = *reinterpret_cast<const short8*>(bp + (0 * 8 + ct) * 512 + lane * 8);
        short8 vz = *reinterpret_cast<const short8*>(bp + (1 * 8 + ct) * 512 + lane * 8);
        short8 vn = *reinterpret_cast<const short8*>(bp + (2 * 8 + ct) * 512 + lane * 8);
        __builtin_amdgcn_s_setprio(1);
        ar = __builtin_amdgcn_mfma_f32_32x32x16_bf16(a, vr, ar, 0, 0, 0);
        az = __builtin_amdgcn_mfma_f32_32x32x16_bf16(a, vz, az, 0, 0, 0);
        if (p < 16) anx = __builtin_amdgcn_mfma_f32_32x32x16_bf16(a, vn, anx, 0, 0, 0);
        else        anh = __builtin_amdgcn_mfma_f32_32x32x16_bf16(a, vn, anh, 0, 0, 0);
        __builtin_amdgcn_s_setprio(0);
    }
    // fused GRU epilogue; H0 rows are L2-hot (staged by this block above)
    int cg = ct * 32 + l31;
    float rb = bih[cg] + bhh[cg];
    float zb = bih[256 + cg] + bhh[256 + cg];
    float bin = bih[512 + cg], bhn = bhh[512 + cg];
    #pragma unroll
    for (int r = 0; r < 16; ++r){
        int m = m0 + rt * 32 + (r & 3) + 8 * (r >> 2) + 4 * half;
        if (m < N_DSTN){
            float h0v = H0[(size_t)m * 256 + cg];
            float rrg = 1.f / (1.f + __expf(-(ar[r] + rb)));
            float zg  = 1.f / (1.f + __expf(-(az[r] + zb)));
            float nx = anx[r] + bin + rrg * (anh[r] + bhn);
            float tm = __expf(-2.f * fabsf(nx));
            float nn = (1.f - tm) / (1.f + tm);
            nn = (nx >= 0.f) ? nn : -nn;
            outH[(size_t)m * 256 + cg] = (1.f - zg) * nn + zg * h0v;
        }
    }
}

// ---- logits = h @ W_out + b_out ------------------------------------------
__global__ __launch_bounds__(256) void logits_kernel(
        const float* __restrict__ H, const float* __restrict__ Wout,
        const float* __restrict__ bout, float* __restrict__ outL){
    __shared__ float Hl[16 * 260];
    __shared__ float Wl[16 * 260];
    int tid = threadIdx.x;
    int m0 = blockIdx.x * 16;
    #pragma unroll
    for (int i = 0; i < 4; ++i){
        int ci = tid + i * 256;
        int row = ci >> 6;
        int c4 = (ci & 63) << 2;
        int gr = m0 + row; if (gr >= N_DSTN) gr = N_DSTN - 1;
        float4 v = *reinterpret_cast<const float4*>(H + (size_t)gr * 256 + c4);
        float* dp = Hl + row * 260 + c4;
        dp[0] = v.x; dp[1] = v.y; dp[2] = v.z; dp[3] = v.w;
    }
    #pragma unroll
    for (int i = 0; i < 16; ++i){
        int ci = tid + i * 256;
        int c = ci >> 4, j = ci & 15;
        Wl[j * 260 + c] = Wout[c * 16 + j];
    }
    __syncthreads();
    int row = tid >> 4, j = tid & 15;
    const float* hr = Hl + row * 260;
    const float* wr = Wl + j * 260;
    float acc = bout[j];
    #pragma unroll
    for (int c = 0; c < 256; c += 4){
        float4 hv = *reinterpret_cast<const float4*>(hr + c);
        float4 wv = *reinterpret_cast<const float4*>(wr + c);
        acc = fmaf(hv.x, wv.x, fmaf(hv.y, wv.y, fmaf(hv.z, wv.z, fmaf(hv.w, wv.w, acc))));
    }
    int m = m0 + row;
    if (m < N_DSTN) outL[m * 16 + j] = acc;
}

extern "C" void kernel_launch(void* const* d_in, const int* in_sizes, int n_in,
                              void* d_out, int out_size, void* d_ws, size_t ws_size,
                              hipStream_t stream){
    const float* feat_gt = (const float*)d_in[0];
    const float* feat_ag = (const float*)d_in[1];
    const float* h0      = (const float*)d_in[2];
    const int*   e_src   = (const int*)d_in[3];
    const int*   e_dst   = (const int*)d_in[4];
    const float* W_src   = (const float*)d_in[5];
    const float* b_src   = (const float*)d_in[6];
    const float* W_dst   = (const float*)d_in[7];
    const float* b_dst   = (const float*)d_in[8];
    const float* attn    = (const float*)d_in[9];
    const float* W_res   = (const float*)d_in[10];
    const float* b_res   = (const float*)d_in[11];
    const float* W_ih    = (const float*)d_in[12];
    const float* W_hh    = (const float*)d_in[13];
    const float* b_ih    = (const float*)d_in[14];
    const float* b_hh    = (const float*)d_in[15];
    const float* W_out   = (const float*)d_in[16];
    const float* b_out   = (const float*)d_in[17];

    float* outL = (float*)d_out;
    float* outH = outL + (size_t)N_DSTN * 16;

    char* ws = (char*)d_ws;
    size_t off = 0;
    auto alloc = [&](size_t bytes) -> void* {
        void* p = ws + off; off = (off + bytes + 255) & ~(size_t)255; return p;
    };
    unsigned short* fs   = (unsigned short*)alloc((size_t)N_SRCN * 256 * 2);
    unsigned short* fd   = (unsigned short*)alloc((size_t)N_DSTN * 256 * 2);
    unsigned short* res  = (unsigned short*)alloc((size_t)N_DSTN * 256 * 2);
    unsigned short* xb   = (unsigned short*)alloc((size_t)N_DSTN * 256 * 2);
    unsigned short* Wt2  = (unsigned short*)alloc(49152 * 2);
    unsigned short* Wf   = (unsigned short*)alloc(393216 * 2);
    int* deg    = (int*)alloc(N_DSTN * 4);
    int* ptr    = (int*)alloc(N_DSTN * 4);
    int* cursor = (int*)alloc(N_DSTN * 4);
    int* csr    = (int*)alloc((size_t)NE * 4);
    int* bsum   = (int*)alloc(256 * 4);
    int* boff   = (int*)alloc(256 * 4);

    hipMemsetAsync(deg, 0, N_DSTN * 4, stream);
    pack_kernel<<<1728, 256, 0, stream>>>(W_src, W_dst, W_res, W_ih, W_hh, Wt2, Wf);

    proj_kernel<<<dim3(4, 782, 3), 256, 0, stream>>>(feat_gt, feat_ag, Wt2,
                                                     b_src, b_dst, b_res, fs, fd, res);

    degree_kernel<<<3125, 256, 0, stream>>>(e_dst, deg);
    scan1_kernel<<<196, 256, 0, stream>>>(deg, bsum);
    scan2_kernel<<<1, 256, 0, stream>>>(bsum, boff);
    scan3_kernel<<<196, 256, 0, stream>>>(deg, boff, ptr, cursor);
    scatter_kernel<<<3125, 256, 0, stream>>>(e_src, e_dst, cursor, csr);
    aggregate_kernel<<<12500, 256, 0, stream>>>(fs, fd, res, attn, ptr, deg, csr, xb);

    gru_kernel<<<782, 1024, 0, stream>>>(xb, h0, Wf, b_ih, b_hh, outH);
    logits_kernel<<<3125, 256, 0, stream>>>(outH, W_out, b_out, outL);
}